// Round 1
// baseline (1848.259 us; speedup 1.0000x reference)
//
#include <hip/hip_runtime.h>
#include <hip/hip_bf16.h>
#include <math.h>

// Problem constants
#define H_   8
#define DK_  64
#define INNER_ 512
#define B_   8
#define T_   1024
#define D_   512
#define PLEN_ 2047   // 2*T-1

// ---------------------------------------------------------------------------
// Generic f32 tiled GEMM:  C[M,N] = A[M,K] @ W[K,N] + bias  (row-major)
// 64x64 tile, BK=16, 256 threads, each thread 4x4.
// ---------------------------------------------------------------------------
__global__ __launch_bounds__(256) void gemm_f32(
    const float* __restrict__ A, int lda,
    const float* __restrict__ W, int ldw,
    const float* __restrict__ bias,
    float* __restrict__ C, int ldc,
    int M, int N, int K)
{
    __shared__ float As[64][17];
    __shared__ float Ws[16][65];
    const int tid = threadIdx.x;
    const int tx = tid & 15, ty = tid >> 4;
    const int row0 = blockIdx.y * 64, col0 = blockIdx.x * 64;

    float acc[4][4] = {};

    for (int k0 = 0; k0 < K; k0 += 16) {
        // A tile: 64 rows x 16 cols  (one float4 per thread)
        {
            int r = tid >> 2, c = (tid & 3) << 2;
            int gr = row0 + r;
            float4 v = make_float4(0.f, 0.f, 0.f, 0.f);
            if (gr < M) v = *(const float4*)(A + (size_t)gr * lda + k0 + c);
            As[r][c]   = v.x; As[r][c+1] = v.y;
            As[r][c+2] = v.z; As[r][c+3] = v.w;
        }
        // W tile: 16 rows x 64 cols (one float4 per thread)
        {
            int r = tid >> 4, c = (tid & 15) << 2;
            float4 v = *(const float4*)(W + (size_t)(k0 + r) * ldw + col0 + c);
            Ws[r][c]   = v.x; Ws[r][c+1] = v.y;
            Ws[r][c+2] = v.z; Ws[r][c+3] = v.w;
        }
        __syncthreads();
        #pragma unroll
        for (int kk = 0; kk < 16; ++kk) {
            float a[4], w[4];
            #pragma unroll
            for (int i = 0; i < 4; ++i) a[i] = As[ty*4 + i][kk];
            #pragma unroll
            for (int j = 0; j < 4; ++j) w[j] = Ws[kk][tx*4 + j];
            #pragma unroll
            for (int i = 0; i < 4; ++i)
                #pragma unroll
                for (int j = 0; j < 4; ++j)
                    acc[i][j] += a[i] * w[j];
        }
        __syncthreads();
    }

    #pragma unroll
    for (int i = 0; i < 4; ++i) {
        int gr = row0 + ty*4 + i;
        if (gr >= M) continue;
        #pragma unroll
        for (int j = 0; j < 4; ++j) {
            int gc = col0 + tx*4 + j;
            float bv = bias ? bias[gc] : 0.f;
            C[(size_t)gr * ldc + gc] = acc[i][j] + bv;
        }
    }
}

// ---------------------------------------------------------------------------
// Flash-style rel-pos attention.
//   scores[b,h,q,k] = ((Q[b,q,h]+u[h])·K[b,k,h] + (Q[b,q,h]+v[h])·P[k-q+T-1,h]) / 8
//   out[b,q,h,:]    = softmax_k(scores) @ V[b,k,h,:]
// rel_shift resolved analytically: pos row index = k - q + (T-1), always in
// [0, 2T-2]. One block = one (b, h, 32-row q tile); K/V/P staged per 32-chunk.
// ---------------------------------------------------------------------------
#define QT 32
#define KT 32

__global__ __launch_bounds__(256) void attn_f32(
    const float* __restrict__ Qp, const float* __restrict__ Kp,
    const float* __restrict__ Vp, const float* __restrict__ Pp,
    const float* __restrict__ bu, const float* __restrict__ bv,
    float* __restrict__ att)
{
    __shared__ float sQ[QT][DK_ + 1];
    __shared__ float sK[KT][DK_ + 1];
    __shared__ float sV[KT][DK_ + 1];
    __shared__ float sP[QT + KT - 1][DK_ + 1];   // 63 pos rows per chunk
    __shared__ float sS[QT][KT + 1];
    __shared__ float sU[DK_], sVb[DK_];

    const int t  = threadIdx.x;
    const int q0 = blockIdx.x * QT;
    const int h  = blockIdx.y;
    const int b  = blockIdx.z;

    if (t < DK_) { sU[t] = bu[h*DK_ + t]; sVb[t] = bv[h*DK_ + t]; }

    // Q tile: QT x DK (float4 loads)
    for (int e = t; e < QT * DK_ / 4; e += 256) {
        int r = e >> 4, c = (e & 15) << 2;
        float4 v = *(const float4*)(Qp + (size_t)(b*T_ + q0 + r) * INNER_ + h*DK_ + c);
        sQ[r][c] = v.x; sQ[r][c+1] = v.y; sQ[r][c+2] = v.z; sQ[r][c+3] = v.w;
    }

    const int r = t >> 3;   // q row within tile (0..31)
    const int g = t & 7;    // octet within row

    float m = -INFINITY, l = 0.f;
    float acc[8];
    #pragma unroll
    for (int i = 0; i < 8; ++i) acc[i] = 0.f;

    for (int k0 = 0; k0 < T_; k0 += KT) {
        __syncthreads();   // prev PV done (and sQ/sU visible on first iter)

        // K, V tiles
        for (int e = t; e < KT * DK_ / 4; e += 256) {
            int rr = e >> 4, c = (e & 15) << 2;
            size_t off = (size_t)(b*T_ + k0 + rr) * INNER_ + h*DK_ + c;
            float4 kv = *(const float4*)(Kp + off);
            sK[rr][c]=kv.x; sK[rr][c+1]=kv.y; sK[rr][c+2]=kv.z; sK[rr][c+3]=kv.w;
            float4 vv = *(const float4*)(Vp + off);
            sV[rr][c]=vv.x; sV[rr][c+1]=vv.y; sV[rr][c+2]=vv.z; sV[rr][c+3]=vv.w;
        }
        // P rows: p = k - q + (T-1), staged range base = k0 - q0 + (T - QT)
        const int p_base = k0 - q0 + (T_ - QT);
        for (int e = t; e < (QT + KT - 1) * DK_ / 4; e += 256) {
            int rr = e >> 4, c = (e & 15) << 2;
            float4 pv = *(const float4*)(Pp + (size_t)(p_base + rr) * INNER_ + h*DK_ + c);
            sP[rr][c]=pv.x; sP[rr][c+1]=pv.y; sP[rr][c+2]=pv.z; sP[rr][c+3]=pv.w;
        }
        __syncthreads();

        // scores: this thread covers k columns g*4 .. g*4+3
        float s[4] = {0.f, 0.f, 0.f, 0.f};
        #pragma unroll 4
        for (int d = 0; d < DK_; ++d) {
            float qd = sQ[r][d];
            float qu = qd + sU[d];
            float qv = qd + sVb[d];
            #pragma unroll
            for (int j = 0; j < 4; ++j) {
                int kk = g*4 + j;
                s[j] += qu * sK[kk][d] + qv * sP[kk - r + (QT - 1)][d];
            }
        }
        float cmax = -INFINITY;
        #pragma unroll
        for (int j = 0; j < 4; ++j) { s[j] *= 0.125f; cmax = fmaxf(cmax, s[j]); }
        cmax = fmaxf(cmax, __shfl_xor(cmax, 1));
        cmax = fmaxf(cmax, __shfl_xor(cmax, 2));
        cmax = fmaxf(cmax, __shfl_xor(cmax, 4));

        float newm  = fmaxf(m, cmax);
        float scale = expf(m - newm);     // first iter: exp(-inf) = 0
        float lsum  = 0.f;
        float p4[4];
        #pragma unroll
        for (int j = 0; j < 4; ++j) { p4[j] = expf(s[j] - newm); lsum += p4[j]; }
        lsum += __shfl_xor(lsum, 1);
        lsum += __shfl_xor(lsum, 2);
        lsum += __shfl_xor(lsum, 4);
        l = l * scale + lsum;
        m = newm;

        #pragma unroll
        for (int j = 0; j < 4; ++j) sS[r][g*4 + j] = p4[j];
        #pragma unroll
        for (int i = 0; i < 8; ++i) acc[i] *= scale;
        __syncthreads();

        // PV: acc dims d = g*8 .. g*8+7
        #pragma unroll 4
        for (int kk = 0; kk < KT; ++kk) {
            float p = sS[r][kk];
            #pragma unroll
            for (int i = 0; i < 8; ++i) acc[i] += p * sV[kk][g*8 + i];
        }
    }

    float inv = 1.f / l;
    size_t obase = (size_t)(b*T_ + q0 + r) * INNER_ + h*DK_ + g*8;
    #pragma unroll
    for (int i = 0; i < 8; ++i) att[obase + i] = acc[i] * inv;
}

// ---------------------------------------------------------------------------
// Launch: X@Wqkv -> {Q,K,V}@W* -> pos@Wpos -> attention -> @Wao -> @Wo
// Workspace (floats): qkv(12.58M) reused for att/ao after projections;
// qp/kp/vp (4.19M each); pp (1.05M). Total ~105 MB.
// ---------------------------------------------------------------------------
extern "C" void kernel_launch(void* const* d_in, const int* in_sizes, int n_in,
                              void* d_out, int out_size, void* d_ws, size_t ws_size,
                              hipStream_t stream)
{
    const float* x     = (const float*)d_in[0];
    const float* pos   = (const float*)d_in[1];
    const float* w_qkv = (const float*)d_in[2];
    const float* w_q   = (const float*)d_in[3];
    const float* b_q   = (const float*)d_in[4];
    const float* w_k   = (const float*)d_in[5];
    const float* b_k   = (const float*)d_in[6];
    const float* w_v   = (const float*)d_in[7];
    const float* b_v   = (const float*)d_in[8];
    const float* w_pos = (const float*)d_in[9];
    const float* bu    = (const float*)d_in[10];
    const float* bv    = (const float*)d_in[11];
    const float* w_ao  = (const float*)d_in[12];
    const float* b_ao  = (const float*)d_in[13];
    const float* w_o   = (const float*)d_in[14];
    const float* b_o   = (const float*)d_in[15];
    float* out = (float*)d_out;
    float* ws  = (float*)d_ws;

    const size_t BT = (size_t)B_ * T_;          // 8192
    float* qkv = ws;                            // BT * 1536
    float* att = ws;                            // reuses qkv (dead after projections)
    float* ao  = ws + BT * (size_t)INNER_;      // second slot inside qkv region
    float* qp  = ws + BT * 1536;                // BT * 512
    float* kp  = qp + BT * (size_t)INNER_;
    float* vp  = kp + BT * (size_t)INNER_;
    float* pp  = vp + BT * (size_t)INNER_;      // PLEN * 512

    dim3 blk(256);

    // 1) qkv = x @ w_qkv
    gemm_f32<<<dim3(1536/64, BT/64), blk, 0, stream>>>(
        x, D_, w_qkv, 3*INNER_, nullptr, qkv, 3*INNER_, (int)BT, 3*INNER_, D_);
    // 2-4) q/k/v projections (strided slices of qkv)
    gemm_f32<<<dim3(INNER_/64, BT/64), blk, 0, stream>>>(
        qkv,            3*INNER_, w_q, INNER_, b_q, qp, INNER_, (int)BT, INNER_, INNER_);
    gemm_f32<<<dim3(INNER_/64, BT/64), blk, 0, stream>>>(
        qkv + INNER_,   3*INNER_, w_k, INNER_, b_k, kp, INNER_, (int)BT, INNER_, INNER_);
    gemm_f32<<<dim3(INNER_/64, BT/64), blk, 0, stream>>>(
        qkv + 2*INNER_, 3*INNER_, w_v, INNER_, b_v, vp, INNER_, (int)BT, INNER_, INNER_);
    // 5) pos projection (M=2047, guarded)
    gemm_f32<<<dim3(INNER_/64, (PLEN_ + 63)/64), blk, 0, stream>>>(
        pos, INNER_, w_pos, INNER_, nullptr, pp, INNER_, PLEN_, INNER_, INNER_);
    // 6) attention (overwrites qkv region with att)
    attn_f32<<<dim3(T_/QT, H_, B_), blk, 0, stream>>>(qp, kp, vp, pp, bu, bv, att);
    // 7) ao = att @ w_ao + b_ao
    gemm_f32<<<dim3(INNER_/64, BT/64), blk, 0, stream>>>(
        att, INNER_, w_ao, INNER_, b_ao, ao, INNER_, (int)BT, INNER_, INNER_);
    // 8) out = ao @ w_o + b_o
    gemm_f32<<<dim3(D_/64, BT/64), blk, 0, stream>>>(
        ao, INNER_, w_o, D_, b_o, out, D_, (int)BT, D_, D_);
}

// Round 2
// 477.623 us; speedup vs baseline: 3.8697x; 3.8697x over previous
//
#include <hip/hip_runtime.h>
#include <hip/hip_bf16.h>
#include <math.h>

#define H_     8
#define DK_    64
#define INNER_ 512
#define B_     8
#define T_     1024
#define D_     512
#define PLEN_  2047
#define BT_    8192
#define KDIM_  512   // K of every dense GEMM

typedef __attribute__((ext_vector_type(8))) short bf16x8;
typedef __attribute__((ext_vector_type(4))) float f32x4;
typedef __attribute__((ext_vector_type(4))) unsigned short u16x4;
typedef __attribute__((ext_vector_type(8))) unsigned short u16x8;

__device__ __forceinline__ unsigned short f2bf(float f) {
    unsigned u = __float_as_uint(f);
    u += 0x7fffu + ((u >> 16) & 1u);
    return (unsigned short)(u >> 16);
}
__device__ __forceinline__ float bf2f(unsigned short s) {
    return __uint_as_float(((unsigned)s) << 16);
}
__device__ __forceinline__ f32x4 mfma16(bf16x8 a, bf16x8 b, f32x4 c) {
    return __builtin_amdgcn_mfma_f32_16x16x32_bf16(a, b, c, 0, 0, 0);
}

// ---------------------------------------------------------------------------
// prep_w: w[K=512][N] f32  ->  wh/wl[N][512] bf16 (transposed + hi/lo split)
// ---------------------------------------------------------------------------
__global__ __launch_bounds__(256) void prep_w(
    const float* __restrict__ w, unsigned short* __restrict__ wh,
    unsigned short* __restrict__ wl, int N)
{
    __shared__ float sW[32][36];
    const int t = threadIdx.x;
    const int n0 = blockIdx.x * 32, k0 = blockIdx.y * 32;
    {
        int kr = t >> 3, c4 = (t & 7) * 4;
        f32x4 v = *(const f32x4*)(w + (size_t)(k0 + kr) * N + n0 + c4);
        #pragma unroll
        for (int i = 0; i < 4; ++i) sW[kr][c4 + i] = v[i];
    }
    __syncthreads();
    {
        int nr = t >> 3, kc = (t & 7) * 4;
        u16x4 hv, lv;
        #pragma unroll
        for (int i = 0; i < 4; ++i) {
            float f = sW[kc + i][nr];
            unsigned short hb = f2bf(f);
            hv[i] = hb;
            lv[i] = f2bf(f - bf2f(hb));
        }
        *(u16x4*)(wh + (size_t)(n0 + nr) * KDIM_ + k0 + kc) = hv;
        *(u16x4*)(wl + (size_t)(n0 + nr) * KDIM_ + k0 + kc) = lv;
    }
}

// ---------------------------------------------------------------------------
// gemm_split: C[M,N] = A[M,512] @ W[512,N] (+bias), split-bf16 (3 MFMAs).
// 128x128 tile, BK=32, 256 threads = 4 waves (2x2 of 64x64).
// ---------------------------------------------------------------------------
__global__ __launch_bounds__(256, 2) void gemm_split(
    const float* __restrict__ A, int lda,
    const unsigned short* __restrict__ wh_g,
    const unsigned short* __restrict__ wl_g,
    const float* __restrict__ bias,
    float* __restrict__ C, int N, int M)
{
    __shared__ __align__(16) unsigned short Ah[128][32];
    __shared__ __align__(16) unsigned short Al[128][32];
    __shared__ __align__(16) unsigned short Wh[128][32];
    __shared__ __align__(16) unsigned short Wl[128][32];

    const int t = threadIdx.x;
    const int lane = t & 63, w = t >> 6;
    const int wm = w >> 1, wn = w & 1;
    const int ln15 = lane & 15, g4 = lane >> 4;
    const int ak = g4 * 8;
    const int row0 = blockIdx.y * 128, col0 = blockIdx.x * 128;

    f32x4 acc[4][4];
    #pragma unroll
    for (int i = 0; i < 4; ++i)
        #pragma unroll
        for (int j = 0; j < 4; ++j)
            acc[i][j] = (f32x4){0.f, 0.f, 0.f, 0.f};

    for (int kt = 0; kt < 16; ++kt) {
        __syncthreads();
        // A tile (f32 -> hi/lo bf16): 128 rows x 32 cols = 1024 float4 slots
        #pragma unroll
        for (int i = 0; i < 4; ++i) {
            int e = t + 256 * i;
            int r = e >> 3, c = (e & 7) * 4;
            int gr = row0 + r;
            f32x4 v = {0.f, 0.f, 0.f, 0.f};
            if (gr < M) v = *(const f32x4*)(A + (size_t)gr * lda + kt * 32 + c);
            u16x4 hv, lv;
            #pragma unroll
            for (int j = 0; j < 4; ++j) {
                unsigned short hb = f2bf(v[j]);
                hv[j] = hb;
                lv[j] = f2bf(v[j] - bf2f(hb));
            }
            *(u16x4*)&Ah[r][c] = hv;
            *(u16x4*)&Al[r][c] = lv;
        }
        // W tiles (already bf16 [N][512]): 128 rows x 32 cols, 16B chunks
        #pragma unroll
        for (int i = 0; i < 2; ++i) {
            int e = t + 256 * i;
            int r = e >> 2, c = (e & 3) * 8;
            *(u16x8*)&Wh[r][c] = *(const u16x8*)(wh_g + (size_t)(col0 + r) * KDIM_ + kt * 32 + c);
            *(u16x8*)&Wl[r][c] = *(const u16x8*)(wl_g + (size_t)(col0 + r) * KDIM_ + kt * 32 + c);
        }
        __syncthreads();

        bf16x8 fah[4], fal[4], fwh[4], fwl[4];
        #pragma unroll
        for (int i = 0; i < 4; ++i) {
            int ar = wm * 64 + i * 16 + ln15;
            fah[i] = *(const bf16x8*)&Ah[ar][ak];
            fal[i] = *(const bf16x8*)&Al[ar][ak];
            int wr = wn * 64 + i * 16 + ln15;
            fwh[i] = *(const bf16x8*)&Wh[wr][ak];
            fwl[i] = *(const bf16x8*)&Wl[wr][ak];
        }
        #pragma unroll
        for (int mi = 0; mi < 4; ++mi)
            #pragma unroll
            for (int ni = 0; ni < 4; ++ni) {
                acc[mi][ni] = mfma16(fah[mi], fwh[ni], acc[mi][ni]);
                acc[mi][ni] = mfma16(fah[mi], fwl[ni], acc[mi][ni]);
                acc[mi][ni] = mfma16(fal[mi], fwh[ni], acc[mi][ni]);
            }
    }

    #pragma unroll
    for (int mi = 0; mi < 4; ++mi)
        #pragma unroll
        for (int r4 = 0; r4 < 4; ++r4) {
            int gr = row0 + wm * 64 + mi * 16 + g4 * 4 + r4;
            if (gr < M) {
                #pragma unroll
                for (int ni = 0; ni < 4; ++ni) {
                    int gc = col0 + wn * 64 + ni * 16 + ln15;
                    float bv = bias ? bias[gc] : 0.f;
                    C[(size_t)gr * N + gc] = acc[mi][ni][r4] + bv;
                }
            }
        }
}

// ---------------------------------------------------------------------------
// prep_quvk: qu = bf16(qp+bu), qv = bf16(qp+bv), kb = bf16(kp)   (elementwise)
// ---------------------------------------------------------------------------
__global__ __launch_bounds__(256) void prep_quvk(
    const float* __restrict__ qp, const float* __restrict__ kp,
    const float* __restrict__ bu, const float* __restrict__ bv,
    unsigned short* __restrict__ qu, unsigned short* __restrict__ qv,
    unsigned short* __restrict__ kb)
{
    size_t i4 = ((size_t)blockIdx.x * 256 + threadIdx.x) * 4;
    int col = (int)(i4 & (INNER_ - 1));
    f32x4 q = *(const f32x4*)(qp + i4);
    f32x4 k = *(const f32x4*)(kp + i4);
    f32x4 u = *(const f32x4*)(bu + col);
    f32x4 v = *(const f32x4*)(bv + col);
    u16x4 a, bb, c;
    #pragma unroll
    for (int i = 0; i < 4; ++i) {
        a[i]  = f2bf(q[i] + u[i]);
        bb[i] = f2bf(q[i] + v[i]);
        c[i]  = f2bf(k[i]);
    }
    *(u16x4*)(qu + i4) = a;
    *(u16x4*)(qv + i4) = bb;
    *(u16x4*)(kb + i4) = c;
}

// ---------------------------------------------------------------------------
// prep_vt: vp[b*T+t][h*64+d] f32 -> vt[((b*8+h)*64+d)*1024 + t] bf16 (transpose)
// ---------------------------------------------------------------------------
__global__ __launch_bounds__(256) void prep_vt(
    const float* __restrict__ vp, unsigned short* __restrict__ vt)
{
    __shared__ __align__(16) unsigned short sT[64][72];
    const int t = threadIdx.x;
    const int t0 = blockIdx.x * 64;
    const int h = blockIdx.y, b = blockIdx.z;
    for (int e = t; e < 64 * 16; e += 256) {
        int r = e >> 4, c4 = (e & 15) * 4;
        f32x4 v = *(const f32x4*)(vp + ((size_t)b * T_ + t0 + r) * INNER_ + h * DK_ + c4);
        #pragma unroll
        for (int i = 0; i < 4; ++i) sT[c4 + i][r] = f2bf(v[i]);
    }
    __syncthreads();
    for (int e = t; e < 64 * 4; e += 256) {
        int d = e >> 2, tc = (e & 3) * 16;
        u16x8 x0 = *(const u16x8*)&sT[d][tc];
        u16x8 x1 = *(const u16x8*)&sT[d][tc + 8];
        unsigned short* dst = vt + ((size_t)(b * H_ + h) * DK_ + d) * T_ + t0 + tc;
        *(u16x8*)dst = x0;
        *(u16x8*)(dst + 8) = x1;
    }
}

// ---------------------------------------------------------------------------
// prep_p: pb region (512-slot zero slack, then bf16(pp) for 2047*512 elems)
// ---------------------------------------------------------------------------
__global__ __launch_bounds__(256) void prep_p(
    const float* __restrict__ pp, unsigned short* __restrict__ pb_base)
{
    size_t i4 = ((size_t)blockIdx.x * 256 + threadIdx.x) * 4;
    u16x4 o;
    #pragma unroll
    for (int i = 0; i < 4; ++i) {
        size_t idx = i4 + i;
        o[i] = (idx < 512) ? (unsigned short)0 : f2bf(pp[idx - 512]);
    }
    *(u16x4*)(pb_base + i4) = o;
}

// ---------------------------------------------------------------------------
// attn_mfma: flash rel-pos attention, bf16 MFMA, BD via ring buffer.
// block = (b, h, 64-row q tile), 256 threads = 4 waves (16 q rows each).
// scores[q,k] = (qu.K + qv.P[k-q+1023]) * 0.125 ; out = softmax @ V
// ---------------------------------------------------------------------------
__global__ __launch_bounds__(256, 2) void attn_mfma(
    const unsigned short* __restrict__ qu_g,
    const unsigned short* __restrict__ qv_g,
    const unsigned short* __restrict__ kb_g,
    const unsigned short* __restrict__ vt_g,
    const unsigned short* __restrict__ pb_g,   // points at p=0 (zeroed slack before)
    float* __restrict__ att)
{
    __shared__ __align__(16) unsigned short sK[64][72];
    __shared__ __align__(16) unsigned short sP[64][72];
    __shared__ __align__(16) unsigned short sV[64][72];   // [d][token]
    __shared__ __align__(16) float ring[64][132];
    __shared__ __align__(16) unsigned short sProb[64][80];

    const int t = threadIdx.x;
    const int lane = t & 63, w = t >> 6;
    const int ln15 = lane & 15, g4 = lane >> 4;
    const int ak = g4 * 8;
    const int q0 = blockIdx.x * 64;
    const int h = blockIdx.y, b = blockIdx.z;
    const size_t tok0 = (size_t)b * T_;
    const int hd = h * DK_;

    // stage Qu -> sK, Qv -> sP; pull fragments to registers
    for (int e = t; e < 64 * 8; e += 256) {
        int r = e >> 3, c = (e & 7) * 8;
        *(u16x8*)&sK[r][c] = *(const u16x8*)(qu_g + (tok0 + q0 + r) * INNER_ + hd + c);
        *(u16x8*)&sP[r][c] = *(const u16x8*)(qv_g + (tok0 + q0 + r) * INNER_ + hd + c);
    }
    __syncthreads();
    bf16x8 fqu[2], fqv[2];
    {
        int ar = w * 16 + ln15;
        fqu[0] = *(const bf16x8*)&sK[ar][ak];
        fqu[1] = *(const bf16x8*)&sK[ar][ak + 32];
        fqv[0] = *(const bf16x8*)&sP[ar][ak];
        fqv[1] = *(const bf16x8*)&sP[ar][ak + 32];
    }
    __syncthreads();

    // prologue BD piece: P rows p = 959 - q0 + i  -> ring pos 0..63
    for (int e = t; e < 64 * 8; e += 256) {
        int r = e >> 3, c = (e & 7) * 8;
        long p = (long)(959 - q0 + r);
        *(u16x8*)&sP[r][c] = *(const u16x8*)(pb_g + p * INNER_ + hd + c);
    }
    __syncthreads();
    #pragma unroll
    for (int n = 0; n < 4; ++n) {
        f32x4 bd = {0.f, 0.f, 0.f, 0.f};
        #pragma unroll
        for (int ki = 0; ki < 2; ++ki) {
            bf16x8 pf = *(const bf16x8*)&sP[n * 16 + ln15][ak + ki * 32];
            bd = mfma16(fqv[ki], pf, bd);
        }
        #pragma unroll
        for (int r4 = 0; r4 < 4; ++r4)
            ring[w * 16 + g4 * 4 + r4][n * 16 + ln15] = bd[r4];
    }

    float m_r[4], l_r[4];
    f32x4 o[4];
    #pragma unroll
    for (int i = 0; i < 4; ++i) {
        m_r[i] = -INFINITY; l_r[i] = 0.f;
        o[i] = (f32x4){0.f, 0.f, 0.f, 0.f};
    }

    for (int c = 0; c < 16; ++c) {
        __syncthreads();   // previous chunk's reads of sK/sP/sV complete
        for (int e = t; e < 64 * 8; e += 256) {
            int r = e >> 3, cc = (e & 7) * 8;
            *(u16x8*)&sK[r][cc] = *(const u16x8*)(kb_g + (tok0 + c * 64 + r) * INNER_ + hd + cc);
            *(u16x8*)&sV[r][cc] = *(const u16x8*)(vt_g + ((size_t)(b * H_ + h) * DK_ + r) * T_ + c * 64 + cc);
            long p = (long)(c * 64 - q0 + 1023 + r);
            *(u16x8*)&sP[r][cc] = *(const u16x8*)(pb_g + p * INNER_ + hd + cc);
        }
        __syncthreads();

        // AC + BD-new MFMAs
        f32x4 sc[4], bd[4];
        #pragma unroll
        for (int n = 0; n < 4; ++n) {
            sc[n] = (f32x4){0.f, 0.f, 0.f, 0.f};
            bd[n] = (f32x4){0.f, 0.f, 0.f, 0.f};
        }
        #pragma unroll
        for (int ki = 0; ki < 2; ++ki)
            #pragma unroll
            for (int n = 0; n < 4; ++n) {
                bf16x8 kf = *(const bf16x8*)&sK[n * 16 + ln15][ak + ki * 32];
                sc[n] = mfma16(fqu[ki], kf, sc[n]);
                bf16x8 pf = *(const bf16x8*)&sP[n * 16 + ln15][ak + ki * 32];
                bd[n] = mfma16(fqv[ki], pf, bd[n]);
            }
        const int pbase = ((c + 1) * 64) & 127;
        #pragma unroll
        for (int n = 0; n < 4; ++n)
            #pragma unroll
            for (int r4 = 0; r4 < 4; ++r4)
                ring[w * 16 + g4 * 4 + r4][pbase + n * 16 + ln15] = bd[n][r4];

        // online softmax (rows qq, 16 lanes per row-group)
        #pragma unroll
        for (int r4 = 0; r4 < 4; ++r4) {
            int qq = w * 16 + g4 * 4 + r4;
            float s4[4];
            float mx = -1e30f;
            #pragma unroll
            for (int n = 0; n < 4; ++n) {
                int kl = n * 16 + ln15;
                int pos = (c * 64 + kl - qq + 64) & 127;
                float s = (sc[n][r4] + ring[qq][pos]) * 0.125f;
                s4[n] = s;
                mx = fmaxf(mx, s);
            }
            mx = fmaxf(mx, __shfl_xor(mx, 1));
            mx = fmaxf(mx, __shfl_xor(mx, 2));
            mx = fmaxf(mx, __shfl_xor(mx, 4));
            mx = fmaxf(mx, __shfl_xor(mx, 8));
            float newm = fmaxf(m_r[r4], mx);
            float scale = __expf(m_r[r4] - newm);
            m_r[r4] = newm;
            float ls = 0.f;
            #pragma unroll
            for (int n = 0; n < 4; ++n) {
                float p = __expf(s4[n] - newm);
                ls += p;
                sProb[qq][n * 16 + ln15] = f2bf(p);
            }
            ls += __shfl_xor(ls, 1);
            ls += __shfl_xor(ls, 2);
            ls += __shfl_xor(ls, 4);
            ls += __shfl_xor(ls, 8);
            l_r[r4] = l_r[r4] * scale + ls;
            #pragma unroll
            for (int n2 = 0; n2 < 4; ++n2) o[n2][r4] *= scale;
        }

        // PV
        #pragma unroll
        for (int ki = 0; ki < 2; ++ki) {
            bf16x8 pa = *(const bf16x8*)&sProb[w * 16 + ln15][ak + ki * 32];
            #pragma unroll
            for (int n2 = 0; n2 < 4; ++n2) {
                bf16x8 vf = *(const bf16x8*)&sV[n2 * 16 + ln15][ak + ki * 32];
                o[n2] = mfma16(pa, vf, o[n2]);
            }
        }
    }

    #pragma unroll
    for (int r4 = 0; r4 < 4; ++r4) {
        float inv = 1.0f / l_r[r4];
        int qq = w * 16 + g4 * 4 + r4;
        #pragma unroll
        for (int n2 = 0; n2 < 4; ++n2)
            att[(tok0 + q0 + qq) * INNER_ + hd + n2 * 16 + ln15] = o[n2][r4] * inv;
    }
}

// ---------------------------------------------------------------------------
extern "C" void kernel_launch(void* const* d_in, const int* in_sizes, int n_in,
                              void* d_out, int out_size, void* d_ws, size_t ws_size,
                              hipStream_t stream)
{
    const float* x     = (const float*)d_in[0];
    const float* pos   = (const float*)d_in[1];
    const float* w_qkv = (const float*)d_in[2];
    const float* w_q   = (const float*)d_in[3];
    const float* b_q   = (const float*)d_in[4];
    const float* w_k   = (const float*)d_in[5];
    const float* b_k   = (const float*)d_in[6];
    const float* w_v   = (const float*)d_in[7];
    const float* b_v   = (const float*)d_in[8];
    const float* w_pos = (const float*)d_in[9];
    const float* bu    = (const float*)d_in[10];
    const float* bv    = (const float*)d_in[11];
    const float* w_ao  = (const float*)d_in[12];
    const float* b_ao  = (const float*)d_in[13];
    const float* w_o   = (const float*)d_in[14];
    const float* b_o   = (const float*)d_in[15];
    float* out = (float*)d_out;
    float* ws  = (float*)d_ws;

    // f32 regions
    float* qkv = ws;                       // [0, 12582912) ; later reused as u16 region
    float* qp  = ws + 12582912;            // 4194304
    float* kp  = ws + 16777216;
    float* vp  = ws + 20971520;
    float* pp  = ws + 25165824;            // 1048064 (pad to 1048576)
    float* att = qp;                       // attention output reuses qp
    float* ao  = kp;                       // reuses kp
    // u16 arrays inside the (dead-after-projections) qkv region
    unsigned short* u16base = (unsigned short*)ws;
    unsigned short* qu = u16base;                      // 4194304 u16
    unsigned short* qv = u16base + 4194304;
    unsigned short* kb = u16base + 8388608;
    unsigned short* vt = u16base + 12582912;
    unsigned short* pb_base = u16base + 16777216;      // 1048576 u16
    unsigned short* pb0 = pb_base + 512;               // p = 0
    // weights region after pp
    unsigned short* wb = (unsigned short*)(ws + 26214400);
    unsigned short* wqkv_h = wb;                 // 786432
    unsigned short* wqkv_l = wb + 786432;
    unsigned short* wq_h   = wb + 1572864;       // 262144 each from here
    unsigned short* wq_l   = wq_h + 262144;
    unsigned short* wk_h   = wq_h + 524288;
    unsigned short* wk_l   = wq_h + 786432;
    unsigned short* wv_h   = wq_h + 1048576;
    unsigned short* wv_l   = wq_h + 1310720;
    unsigned short* wpos_h = wq_h + 1572864;
    unsigned short* wpos_l = wq_h + 1835008;
    unsigned short* wao_h  = wq_h + 2097152;
    unsigned short* wao_l  = wq_h + 2359296;
    unsigned short* wo_h   = wq_h + 2621440;
    unsigned short* wo_l   = wq_h + 2883584;

    dim3 blk(256);

    // 1) weight prep (transpose + split)
    prep_w<<<dim3(48, 16), blk, 0, stream>>>(w_qkv, wqkv_h, wqkv_l, 1536);
    prep_w<<<dim3(16, 16), blk, 0, stream>>>(w_q,   wq_h,   wq_l,   512);
    prep_w<<<dim3(16, 16), blk, 0, stream>>>(w_k,   wk_h,   wk_l,   512);
    prep_w<<<dim3(16, 16), blk, 0, stream>>>(w_v,   wv_h,   wv_l,   512);
    prep_w<<<dim3(16, 16), blk, 0, stream>>>(w_pos, wpos_h, wpos_l, 512);
    prep_w<<<dim3(16, 16), blk, 0, stream>>>(w_ao,  wao_h,  wao_l,  512);
    prep_w<<<dim3(16, 16), blk, 0, stream>>>(w_o,   wo_h,   wo_l,   512);

    // 2) dense GEMMs (split-bf16)
    gemm_split<<<dim3(12, 64), blk, 0, stream>>>(x,          512, wqkv_h, wqkv_l, nullptr, qkv, 1536, BT_);
    gemm_split<<<dim3(4, 64),  blk, 0, stream>>>(qkv,       1536, wq_h,   wq_l,   b_q,    qp,   512, BT_);
    gemm_split<<<dim3(4, 64),  blk, 0, stream>>>(qkv + 512, 1536, wk_h,   wk_l,   b_k,    kp,   512, BT_);
    gemm_split<<<dim3(4, 64),  blk, 0, stream>>>(qkv + 1024,1536, wv_h,   wv_l,   b_v,    vp,   512, BT_);
    gemm_split<<<dim3(4, 16),  blk, 0, stream>>>(pos,        512, wpos_h, wpos_l, nullptr, pp,  512, PLEN_);

    // 3) attention preps (qkv region now dead -> holds bf16 arrays)
    prep_quvk<<<dim3(4096), blk, 0, stream>>>(qp, kp, bu, bv, qu, qv, kb);
    prep_vt<<<dim3(16, 8, 8), blk, 0, stream>>>(vp, vt);
    prep_p<<<dim3(1024), blk, 0, stream>>>(pp, pb_base);

    // 4) attention (writes att = qp region)
    attn_mfma<<<dim3(16, 8, 8), blk, 0, stream>>>(qu, qv, kb, vt, pb0, att);

    // 5) output GEMMs
    gemm_split<<<dim3(4, 64), blk, 0, stream>>>(att, 512, wao_h, wao_l, b_ao, ao, 512, BT_);
    gemm_split<<<dim3(4, 64), blk, 0, stream>>>(ao,  512, wo_h,  wo_l,  b_o,  out, 512, BT_);
}

// Round 3
// 292.743 us; speedup vs baseline: 6.3136x; 1.6315x over previous
//
#include <hip/hip_runtime.h>
#include <hip/hip_bf16.h>
#include <math.h>

#define H_     8
#define DK_    64
#define INNER_ 512
#define B_     8
#define T_     1024
#define D_     512
#define PLEN_  2047
#define BT_    8192

typedef __attribute__((ext_vector_type(8))) short bf16x8;
typedef __attribute__((ext_vector_type(4))) float f32x4;
typedef __attribute__((ext_vector_type(4))) unsigned short u16x4;
typedef __attribute__((ext_vector_type(8))) unsigned short u16x8;

__device__ __forceinline__ unsigned short f2bf(float f) {
    unsigned u = __float_as_uint(f);
    u += 0x7fffu + ((u >> 16) & 1u);
    return (unsigned short)(u >> 16);
}
__device__ __forceinline__ float bf2f(unsigned short s) {
    return __uint_as_float(((unsigned)s) << 16);
}
__device__ __forceinline__ f32x4 mfma16(bf16x8 a, bf16x8 b, f32x4 c) {
    return __builtin_amdgcn_mfma_f32_16x16x32_bf16(a, b, c, 0, 0, 0);
}
__device__ __forceinline__ void gload16(const unsigned short* g, unsigned short* l) {
    __builtin_amdgcn_global_load_lds(
        (const __attribute__((address_space(1))) void*)g,
        (__attribute__((address_space(3))) void*)l,
        16, 0, 0);
}

// ---------------------------------------------------------------------------
// split_rows: f32 -> hi/lo bf16 (same layout)
// ---------------------------------------------------------------------------
__global__ __launch_bounds__(256) void split_rows(
    const float* __restrict__ src, unsigned short* __restrict__ h,
    unsigned short* __restrict__ l, long total)
{
    size_t i4 = ((size_t)blockIdx.x * 256 + threadIdx.x) * 4;
    if (i4 >= (size_t)total) return;
    f32x4 v = *(const f32x4*)(src + i4);
    u16x4 hh, ll;
    #pragma unroll
    for (int i = 0; i < 4; ++i) {
        unsigned short hb = f2bf(v[i]);
        hh[i] = hb;
        ll[i] = f2bf(v[i] - bf2f(hb));
    }
    *(u16x4*)(h + i4) = hh;
    *(u16x4*)(l + i4) = ll;
}

// ---------------------------------------------------------------------------
// prep_wb: batched  w[512][512] f32 -> wh/wl[n][k] bf16 (transpose + split)
// ---------------------------------------------------------------------------
struct PrepW {
    const float* w[5];
    unsigned short* wh[5];
    unsigned short* wl[5];
};
__global__ __launch_bounds__(256) void prep_wb(PrepW p)
{
    const int z = blockIdx.z;
    const float* w = p.w[z];
    unsigned short* wh = p.wh[z];
    unsigned short* wl = p.wl[z];
    __shared__ float sW[32][36];
    const int t = threadIdx.x;
    const int n0 = blockIdx.x * 32, k0 = blockIdx.y * 32;
    {
        int kr = t >> 3, c4 = (t & 7) * 4;
        f32x4 v = *(const f32x4*)(w + (size_t)(k0 + kr) * 512 + n0 + c4);
        #pragma unroll
        for (int i = 0; i < 4; ++i) sW[kr][c4 + i] = v[i];
    }
    __syncthreads();
    {
        int nr = t >> 3, kc = (t & 7) * 4;
        u16x4 hv, lv;
        #pragma unroll
        for (int i = 0; i < 4; ++i) {
            float f = sW[kc + i][nr];
            unsigned short hb = f2bf(f);
            hv[i] = hb;
            lv[i] = f2bf(f - bf2f(hb));
        }
        *(u16x4*)(wh + (size_t)(n0 + nr) * 512 + k0 + kc) = hv;
        *(u16x4*)(wl + (size_t)(n0 + nr) * 512 + k0 + kc) = lv;
    }
}

// ---------------------------------------------------------------------------
// bias_eff = b_ao @ w_o + b_o
// ---------------------------------------------------------------------------
__global__ __launch_bounds__(256) void bias_eff_k(
    const float* __restrict__ b_ao, const float* __restrict__ w_o,
    const float* __restrict__ b_o, float* __restrict__ be)
{
    int n = blockIdx.x * 256 + threadIdx.x;
    float s = b_o[n];
    for (int j = 0; j < 512; ++j) s += b_ao[j] * w_o[(size_t)j * 512 + n];
    be[n] = s;
}

__global__ void zero_pb(unsigned short* pb) {
    ((unsigned int*)pb)[threadIdx.x] = 0u;   // 256 threads x 4B = 512 u16
}

// ---------------------------------------------------------------------------
// gemm_body: C[M,N] = A[M,512] @ W^T  (A,W pre-split bf16; W in [n][k] form)
// 128x128 tile, BK=32, 4 waves, global_load_lds + 16B-slot XOR swizzle.
// Split product: Ah*Wh + Ah*Wl + Al*Wh (3 MFMAs) ~= f32 accuracy.
// Epilogues: 0=f32+bias  1=qu/qv bf16  2=kb bf16  3=vt bf16 transposed  4=pb bf16
// ---------------------------------------------------------------------------
template<int E>
__device__ __forceinline__ void gemm_body(
    const unsigned short* __restrict__ Ah_g,
    const unsigned short* __restrict__ Al_g, int lda,
    const unsigned short* __restrict__ Wh_g,
    const unsigned short* __restrict__ Wl_g,
    const float* __restrict__ b0, const float* __restrict__ b1,
    const float* __restrict__ b2,
    void* __restrict__ o0, void* __restrict__ o1,
    int M, int N, int row0, int col0)
{
    __shared__ __align__(16) unsigned short sAh[128 * 32];
    __shared__ __align__(16) unsigned short sAl[128 * 32];
    __shared__ __align__(16) unsigned short sWh[128 * 32];
    __shared__ __align__(16) unsigned short sWl[128 * 32];

    const int t = threadIdx.x;
    const int lane = t & 63, w = t >> 6;
    const int wm = w >> 1, wn = w & 1;
    const int ln15 = lane & 15, g4 = lane >> 4;

    f32x4 acc[4][4];
    #pragma unroll
    for (int i = 0; i < 4; ++i)
        #pragma unroll
        for (int j = 0; j < 4; ++j)
            acc[i][j] = (f32x4){0.f, 0.f, 0.f, 0.f};

    for (int kt = 0; kt < 16; ++kt) {
        __syncthreads();
        #pragma unroll
        for (int l = 0; l < 2; ++l) {
            const int ubase = w * 128 + l * 64;          // wave-uniform
            const int e16 = ubase + lane;                // per-lane
            const int row = e16 >> 2, slot = e16 & 3;
            const int ss = slot ^ (row & 3);             // pre-swizzled source slot
            const size_t ga = (size_t)(row0 + row) * lda + kt * 32 + ss * 8;
            const size_t gw = (size_t)(col0 + row) * 512 + kt * 32 + ss * 8;
            gload16(Ah_g + ga, &sAh[ubase * 8]);
            gload16(Al_g + ga, &sAl[ubase * 8]);
            gload16(Wh_g + gw, &sWh[ubase * 8]);
            gload16(Wl_g + gw, &sWl[ubase * 8]);
        }
        __syncthreads();

        bf16x8 fah[4], fal[4], fwh[4], fwl[4];
        #pragma unroll
        for (int i = 0; i < 4; ++i) {
            int ar = wm * 64 + i * 16 + ln15;
            int sa = (g4 ^ (ar & 3)) * 8;
            fah[i] = *(const bf16x8*)&sAh[ar * 32 + sa];
            fal[i] = *(const bf16x8*)&sAl[ar * 32 + sa];
            int wr = wn * 64 + i * 16 + ln15;
            int sw = (g4 ^ (wr & 3)) * 8;
            fwh[i] = *(const bf16x8*)&sWh[wr * 32 + sw];
            fwl[i] = *(const bf16x8*)&sWl[wr * 32 + sw];
        }
        #pragma unroll
        for (int mi = 0; mi < 4; ++mi)
            #pragma unroll
            for (int ni = 0; ni < 4; ++ni) {
                acc[mi][ni] = mfma16(fah[mi], fwh[ni], acc[mi][ni]);
                acc[mi][ni] = mfma16(fah[mi], fwl[ni], acc[mi][ni]);
                acc[mi][ni] = mfma16(fal[mi], fwh[ni], acc[mi][ni]);
            }
    }

    if constexpr (E == 3) {
        // vt[(b*512 + gc)*1024 + t] transposed bf16 write
        #pragma unroll
        for (int mi = 0; mi < 4; ++mi) {
            int gr0 = row0 + wm * 64 + mi * 16 + g4 * 4;
            int bb = gr0 >> 10, t0 = gr0 & 1023;
            #pragma unroll
            for (int ni = 0; ni < 4; ++ni) {
                int gc = col0 + wn * 64 + ni * 16 + ln15;
                float bias = b0[gc];
                u16x4 vv;
                #pragma unroll
                for (int r4 = 0; r4 < 4; ++r4) vv[r4] = f2bf(acc[mi][ni][r4] + bias);
                *(u16x4*)((unsigned short*)o0 + ((size_t)(bb * 512 + gc)) * 1024 + t0) = vv;
            }
        }
    } else {
        #pragma unroll
        for (int mi = 0; mi < 4; ++mi)
            #pragma unroll
            for (int r4 = 0; r4 < 4; ++r4) {
                int gr = row0 + wm * 64 + mi * 16 + g4 * 4 + r4;
                if ((E == 0 || E == 4) && gr >= M) continue;
                #pragma unroll
                for (int ni = 0; ni < 4; ++ni) {
                    int gc = col0 + wn * 64 + ni * 16 + ln15;
                    float a = acc[mi][ni][r4];
                    if constexpr (E == 0) {
                        ((float*)o0)[(size_t)gr * N + gc] = a + (b0 ? b0[gc] : 0.f);
                    } else if constexpr (E == 1) {
                        float base = a + b0[gc];
                        ((unsigned short*)o0)[(size_t)gr * 512 + gc] = f2bf(base + b1[gc]);
                        ((unsigned short*)o1)[(size_t)gr * 512 + gc] = f2bf(base + b2[gc]);
                    } else if constexpr (E == 2) {
                        ((unsigned short*)o0)[(size_t)gr * 512 + gc] = f2bf(a + b0[gc]);
                    } else if constexpr (E == 4) {
                        ((unsigned short*)o0)[(size_t)gr * 512 + gc] = f2bf(a);
                    }
                }
            }
    }
}

template<int E>
__global__ __launch_bounds__(256, 2) void gemm_bb(
    const unsigned short* __restrict__ Ah_g,
    const unsigned short* __restrict__ Al_g, int lda,
    const unsigned short* __restrict__ Wh_g,
    const unsigned short* __restrict__ Wl_g,
    const float* __restrict__ b0, const float* __restrict__ b1,
    const float* __restrict__ b2,
    void* __restrict__ o0, void* __restrict__ o1, int M, int N)
{
    gemm_body<E>(Ah_g, Al_g, lda, Wh_g, Wl_g, b0, b1, b2, o0, o1,
                 M, N, blockIdx.y * 128, blockIdx.x * 128);
}

struct WeffA {
    const unsigned short* ah[4];
    const unsigned short* al[4];
    int lda[4];
    const unsigned short* wh[4];
    const unsigned short* wl[4];
    float* c[4];
};
__global__ __launch_bounds__(256, 2) void gemm_weff(WeffA a)
{
    const int z = blockIdx.z;
    gemm_body<0>(a.ah[z], a.al[z], a.lda[z], a.wh[z], a.wl[z],
                 nullptr, nullptr, nullptr, a.c[z], nullptr,
                 512, 512, blockIdx.y * 128, blockIdx.x * 128);
}

// ---------------------------------------------------------------------------
// attn_mfma: flash rel-pos attention, bf16 MFMA, BD via ring buffer.
// block = (b, h, 64-row q tile), 256 threads = 4 waves (16 q rows each).
// Writes split-bf16 output (atth/attl) feeding the out-GEMM directly.
// ---------------------------------------------------------------------------
__global__ __launch_bounds__(256, 2) void attn_mfma(
    const unsigned short* __restrict__ qu_g,
    const unsigned short* __restrict__ qv_g,
    const unsigned short* __restrict__ kb_g,
    const unsigned short* __restrict__ vt_g,
    const unsigned short* __restrict__ pb_g,   // p = 0 (zeroed slack before)
    unsigned short* __restrict__ atth,
    unsigned short* __restrict__ attl)
{
    __shared__ __align__(16) unsigned short sK[64][72];
    __shared__ __align__(16) unsigned short sP[64][72];
    __shared__ __align__(16) unsigned short sV[64][72];   // [d][token]
    __shared__ __align__(16) float ring[64][132];
    __shared__ __align__(16) unsigned short sProb[64][80];

    const int t = threadIdx.x;
    const int lane = t & 63, w = t >> 6;
    const int ln15 = lane & 15, g4 = lane >> 4;
    const int ak = g4 * 8;
    const int q0 = blockIdx.x * 64;
    const int h = blockIdx.y, b = blockIdx.z;
    const size_t tok0 = (size_t)b * T_;
    const int hd = h * DK_;

    for (int e = t; e < 64 * 8; e += 256) {
        int r = e >> 3, c = (e & 7) * 8;
        *(u16x8*)&sK[r][c] = *(const u16x8*)(qu_g + (tok0 + q0 + r) * INNER_ + hd + c);
        *(u16x8*)&sP[r][c] = *(const u16x8*)(qv_g + (tok0 + q0 + r) * INNER_ + hd + c);
    }
    __syncthreads();
    bf16x8 fqu[2], fqv[2];
    {
        int ar = w * 16 + ln15;
        fqu[0] = *(const bf16x8*)&sK[ar][ak];
        fqu[1] = *(const bf16x8*)&sK[ar][ak + 32];
        fqv[0] = *(const bf16x8*)&sP[ar][ak];
        fqv[1] = *(const bf16x8*)&sP[ar][ak + 32];
    }
    __syncthreads();

    // prologue BD: P rows p = 959 - q0 + i  -> ring pos 0..63
    for (int e = t; e < 64 * 8; e += 256) {
        int r = e >> 3, c = (e & 7) * 8;
        long p = (long)(959 - q0 + r);
        *(u16x8*)&sP[r][c] = *(const u16x8*)(pb_g + p * INNER_ + hd + c);
    }
    __syncthreads();
    #pragma unroll
    for (int n = 0; n < 4; ++n) {
        f32x4 bd = {0.f, 0.f, 0.f, 0.f};
        #pragma unroll
        for (int ki = 0; ki < 2; ++ki) {
            bf16x8 pf = *(const bf16x8*)&sP[n * 16 + ln15][ak + ki * 32];
            bd = mfma16(fqv[ki], pf, bd);
        }
        #pragma unroll
        for (int r4 = 0; r4 < 4; ++r4)
            ring[w * 16 + g4 * 4 + r4][n * 16 + ln15] = bd[r4];
    }

    float m_r[4], l_r[4];
    f32x4 o[4];
    #pragma unroll
    for (int i = 0; i < 4; ++i) {
        m_r[i] = -INFINITY; l_r[i] = 0.f;
        o[i] = (f32x4){0.f, 0.f, 0.f, 0.f};
    }

    for (int c = 0; c < 16; ++c) {
        __syncthreads();
        for (int e = t; e < 64 * 8; e += 256) {
            int r = e >> 3, cc = (e & 7) * 8;
            *(u16x8*)&sK[r][cc] = *(const u16x8*)(kb_g + (tok0 + c * 64 + r) * INNER_ + hd + cc);
            *(u16x8*)&sV[r][cc] = *(const u16x8*)(vt_g + ((size_t)(b * H_ + h) * DK_ + r) * T_ + c * 64 + cc);
            long p = (long)(c * 64 - q0 + 1023 + r);
            *(u16x8*)&sP[r][cc] = *(const u16x8*)(pb_g + p * INNER_ + hd + cc);
        }
        __syncthreads();

        f32x4 sc[4], bd[4];
        #pragma unroll
        for (int n = 0; n < 4; ++n) {
            sc[n] = (f32x4){0.f, 0.f, 0.f, 0.f};
            bd[n] = (f32x4){0.f, 0.f, 0.f, 0.f};
        }
        #pragma unroll
        for (int ki = 0; ki < 2; ++ki)
            #pragma unroll
            for (int n = 0; n < 4; ++n) {
                bf16x8 kf = *(const bf16x8*)&sK[n * 16 + ln15][ak + ki * 32];
                sc[n] = mfma16(fqu[ki], kf, sc[n]);
                bf16x8 pf = *(const bf16x8*)&sP[n * 16 + ln15][ak + ki * 32];
                bd[n] = mfma16(fqv[ki], pf, bd[n]);
            }
        const int pbase = ((c + 1) * 64) & 127;
        #pragma unroll
        for (int n = 0; n < 4; ++n)
            #pragma unroll
            for (int r4 = 0; r4 < 4; ++r4)
                ring[w * 16 + g4 * 4 + r4][pbase + n * 16 + ln15] = bd[n][r4];

        #pragma unroll
        for (int r4 = 0; r4 < 4; ++r4) {
            int qq = w * 16 + g4 * 4 + r4;
            float s4[4];
            float mx = -1e30f;
            #pragma unroll
            for (int n = 0; n < 4; ++n) {
                int kl = n * 16 + ln15;
                int pos = (c * 64 + kl - qq + 64) & 127;
                float s = (sc[n][r4] + ring[qq][pos]) * 0.125f;
                s4[n] = s;
                mx = fmaxf(mx, s);
            }
            mx = fmaxf(mx, __shfl_xor(mx, 1));
            mx = fmaxf(mx, __shfl_xor(mx, 2));
            mx = fmaxf(mx, __shfl_xor(mx, 4));
            mx = fmaxf(mx, __shfl_xor(mx, 8));
            float newm = fmaxf(m_r[r4], mx);
            float scale = __expf(m_r[r4] - newm);
            m_r[r4] = newm;
            float ls = 0.f;
            #pragma unroll
            for (int n = 0; n < 4; ++n) {
                float p = __expf(s4[n] - newm);
                ls += p;
                sProb[qq][n * 16 + ln15] = f2bf(p);
            }
            ls += __shfl_xor(ls, 1);
            ls += __shfl_xor(ls, 2);
            ls += __shfl_xor(ls, 4);
            ls += __shfl_xor(ls, 8);
            l_r[r4] = l_r[r4] * scale + ls;
            #pragma unroll
            for (int n2 = 0; n2 < 4; ++n2) o[n2][r4] *= scale;
        }

        #pragma unroll
        for (int ki = 0; ki < 2; ++ki) {
            bf16x8 pa = *(const bf16x8*)&sProb[w * 16 + ln15][ak + ki * 32];
            #pragma unroll
            for (int n2 = 0; n2 < 4; ++n2) {
                bf16x8 vf = *(const bf16x8*)&sV[n2 * 16 + ln15][ak + ki * 32];
                o[n2] = mfma16(pa, vf, o[n2]);
            }
        }
    }

    #pragma unroll
    for (int r4 = 0; r4 < 4; ++r4) {
        float inv = 1.0f / l_r[r4];
        int qq = w * 16 + g4 * 4 + r4;
        #pragma unroll
        for (int n2 = 0; n2 < 4; ++n2) {
            size_t idx = (tok0 + q0 + qq) * INNER_ + hd + n2 * 16 + ln15;
            float val = o[n2][r4] * inv;
            unsigned short hb = f2bf(val);
            atth[idx] = hb;
            attl[idx] = f2bf(val - bf2f(hb));
        }
    }
}

// ---------------------------------------------------------------------------
extern "C" void kernel_launch(void* const* d_in, const int* in_sizes, int n_in,
                              void* d_out, int out_size, void* d_ws, size_t ws_size,
                              hipStream_t stream)
{
    const float* x     = (const float*)d_in[0];
    const float* pos   = (const float*)d_in[1];
    const float* w_qkv = (const float*)d_in[2];
    const float* w_q   = (const float*)d_in[3];
    const float* b_q   = (const float*)d_in[4];
    const float* w_k   = (const float*)d_in[5];
    const float* b_k   = (const float*)d_in[6];
    const float* w_v   = (const float*)d_in[7];
    const float* b_v   = (const float*)d_in[8];
    const float* w_pos = (const float*)d_in[9];
    const float* bu    = (const float*)d_in[10];
    const float* bv    = (const float*)d_in[11];
    const float* w_ao  = (const float*)d_in[12];
    const float* b_ao  = (const float*)d_in[13];
    const float* w_o   = (const float*)d_in[14];
    const float* b_o   = (const float*)d_in[15];
    float* out = (float*)d_out;

    unsigned short* u = (unsigned short*)d_ws;
    const size_t SZ = (size_t)BT_ * INNER_;          // 4,194,304
    unsigned short* xh   = u;
    unsigned short* xl   = xh + SZ;
    unsigned short* qu   = xl + SZ;
    unsigned short* qv   = qu + SZ;
    unsigned short* kb   = qv + SZ;
    unsigned short* vt   = kb + SZ;
    unsigned short* atth = vt + SZ;
    unsigned short* attl = atth + SZ;
    unsigned short* pb_base = attl + SZ;             // 512 slack + 2047*512
    unsigned short* pb0  = pb_base + 512;
    unsigned short* posh = pb_base + 1049600;
    unsigned short* posl = posh + 1049600;
    unsigned short* wqkvh = posl + 1049600;
    unsigned short* wqkvl = wqkvh + 786432;
    unsigned short* waoh  = wqkvl + 786432;
    unsigned short* waol  = waoh + 262144;
    unsigned short* w5    = waol + 262144;   // wq,wk,wv,wo,wp (h,l) x 262144
    unsigned short* wq_h = w5;              unsigned short* wq_l = w5 + 262144;
    unsigned short* wk_h = w5 + 2*262144;   unsigned short* wk_l = w5 + 3*262144;
    unsigned short* wv_h = w5 + 4*262144;   unsigned short* wv_l = w5 + 5*262144;
    unsigned short* wo_h = w5 + 6*262144;   unsigned short* wo_l = w5 + 7*262144;
    unsigned short* wp_h = w5 + 8*262144;   unsigned short* wp_l = w5 + 9*262144;
    float* weffC = (float*)(w5 + 10*262144);           // 4 x 262144 f32
    unsigned short* weffS = (unsigned short*)(weffC + 4*262144);
    unsigned short* wqe_h = weffS;              unsigned short* wqe_l = weffS + 262144;
    unsigned short* wke_h = weffS + 2*262144;   unsigned short* wke_l = weffS + 3*262144;
    unsigned short* wve_h = weffS + 4*262144;   unsigned short* wve_l = weffS + 5*262144;
    unsigned short* woe_h = weffS + 6*262144;   unsigned short* woe_l = weffS + 7*262144;
    float* beff = (float*)(weffS + 8*262144);

    dim3 blk(256);

    // --- preps ---
    split_rows<<<4096, blk, 0, stream>>>(x,     xh,    xl,    (long)SZ);
    split_rows<<<768,  blk, 0, stream>>>(w_qkv, wqkvh, wqkvl, 786432L);
    split_rows<<<256,  blk, 0, stream>>>(w_ao,  waoh,  waol,  262144L);
    split_rows<<<1024, blk, 0, stream>>>(pos,   posh,  posl,  (long)PLEN_ * 512);

    PrepW p5;
    p5.w[0] = w_q;  p5.wh[0] = wq_h; p5.wl[0] = wq_l;
    p5.w[1] = w_k;  p5.wh[1] = wk_h; p5.wl[1] = wk_l;
    p5.w[2] = w_v;  p5.wh[2] = wv_h; p5.wl[2] = wv_l;
    p5.w[3] = w_o;  p5.wh[3] = wo_h; p5.wl[3] = wo_l;
    p5.w[4] = w_pos; p5.wh[4] = wp_h; p5.wl[4] = wp_l;
    prep_wb<<<dim3(16, 16, 5), blk, 0, stream>>>(p5);

    WeffA wa;
    wa.ah[0] = wqkvh;       wa.al[0] = wqkvl;       wa.lda[0] = 1536;
    wa.ah[1] = wqkvh + 512; wa.al[1] = wqkvl + 512; wa.lda[1] = 1536;
    wa.ah[2] = wqkvh + 1024;wa.al[2] = wqkvl + 1024;wa.lda[2] = 1536;
    wa.ah[3] = waoh;        wa.al[3] = waol;        wa.lda[3] = 512;
    wa.wh[0] = wq_h; wa.wl[0] = wq_l;
    wa.wh[1] = wk_h; wa.wl[1] = wk_l;
    wa.wh[2] = wv_h; wa.wl[2] = wv_l;
    wa.wh[3] = wo_h; wa.wl[3] = wo_l;
    wa.c[0] = weffC;             wa.c[1] = weffC + 262144;
    wa.c[2] = weffC + 2*262144;  wa.c[3] = weffC + 3*262144;
    gemm_weff<<<dim3(4, 4, 4), blk, 0, stream>>>(wa);

    PrepW p4;
    p4.w[0] = weffC;            p4.wh[0] = wqe_h; p4.wl[0] = wqe_l;
    p4.w[1] = weffC + 262144;   p4.wh[1] = wke_h; p4.wl[1] = wke_l;
    p4.w[2] = weffC + 2*262144; p4.wh[2] = wve_h; p4.wl[2] = wve_l;
    p4.w[3] = weffC + 3*262144; p4.wh[3] = woe_h; p4.wl[3] = woe_l;
    p4.w[4] = nullptr; p4.wh[4] = nullptr; p4.wl[4] = nullptr;
    prep_wb<<<dim3(16, 16, 4), blk, 0, stream>>>(p4);

    bias_eff_k<<<2, blk, 0, stream>>>(b_ao, w_o, b_o, beff);
    zero_pb<<<1, blk, 0, stream>>>(pb_base);

    // --- main GEMMs ---
    gemm_bb<1><<<dim3(4, 64), blk, 0, stream>>>(xh, xl, 512, wqe_h, wqe_l,
        b_q, bu, bv, qu, qv, BT_, 512);
    gemm_bb<2><<<dim3(4, 64), blk, 0, stream>>>(xh, xl, 512, wke_h, wke_l,
        b_k, nullptr, nullptr, kb, nullptr, BT_, 512);
    gemm_bb<3><<<dim3(4, 64), blk, 0, stream>>>(xh, xl, 512, wve_h, wve_l,
        b_v, nullptr, nullptr, vt, nullptr, BT_, 512);
    gemm_bb<4><<<dim3(4, 16), blk, 0, stream>>>(posh, posl, 512, wp_h, wp_l,
        nullptr, nullptr, nullptr, pb0, nullptr, PLEN_, 512);

    // --- attention ---
    attn_mfma<<<dim3(16, 8, 8), blk, 0, stream>>>(qu, qv, kb, vt, pb0, atth, attl);

    // --- output GEMM ---
    gemm_bb<0><<<dim3(4, 64), blk, 0, stream>>>(atth, attl, 512, woe_h, woe_l,
        beff, nullptr, nullptr, out, nullptr, BT_, 512);
}

// Round 4
// 237.349 us; speedup vs baseline: 7.7871x; 1.2334x over previous
//
#include <hip/hip_runtime.h>
#include <hip/hip_bf16.h>
#include <math.h>

#define H_     8
#define DK_    64
#define INNER_ 512
#define B_     8
#define T_     1024
#define D_     512
#define PLEN_  2047
#define BT_    8192

typedef __attribute__((ext_vector_type(8))) short bf16x8;
typedef __attribute__((ext_vector_type(4))) float f32x4;
typedef __attribute__((ext_vector_type(4))) unsigned short u16x4;
typedef __attribute__((ext_vector_type(8))) unsigned short u16x8;

__device__ __forceinline__ unsigned short f2bf(float f) {
    unsigned u = __float_as_uint(f);
    u += 0x7fffu + ((u >> 16) & 1u);
    return (unsigned short)(u >> 16);
}
__device__ __forceinline__ float bf2f(unsigned short s) {
    return __uint_as_float(((unsigned)s) << 16);
}
__device__ __forceinline__ f32x4 mfma16(bf16x8 a, bf16x8 b, f32x4 c) {
    return __builtin_amdgcn_mfma_f32_16x16x32_bf16(a, b, c, 0, 0, 0);
}
__device__ __forceinline__ void gload16(const unsigned short* g, unsigned short* l) {
    __builtin_amdgcn_global_load_lds(
        (const __attribute__((address_space(1))) void*)g,
        (__attribute__((address_space(3))) void*)l,
        16, 0, 0);
}

// ---------------------------------------------------------------------------
// split4: batched f32 -> hi/lo bf16 split (4 segments, one launch)
// ---------------------------------------------------------------------------
struct SplitA {
    const float* s[4];
    unsigned short* h[4];
    unsigned short* l[4];
    long n[4];
};
__global__ __launch_bounds__(256) void split4(SplitA a)
{
    const int seg = blockIdx.y;
    long i4 = ((long)blockIdx.x * 256 + threadIdx.x) * 4;
    if (i4 >= a.n[seg]) return;
    f32x4 v = *(const f32x4*)(a.s[seg] + i4);
    u16x4 hh, ll;
    #pragma unroll
    for (int i = 0; i < 4; ++i) {
        unsigned short hb = f2bf(v[i]);
        hh[i] = hb;
        ll[i] = f2bf(v[i] - bf2f(hb));
    }
    *(u16x4*)(a.h[seg] + i4) = hh;
    *(u16x4*)(a.l[seg] + i4) = ll;
}

// ---------------------------------------------------------------------------
// prep_wb: batched  w[512][512] f32 -> wh/wl[n][k] bf16 (transpose + split)
// ---------------------------------------------------------------------------
struct PrepW {
    const float* w[5];
    unsigned short* wh[5];
    unsigned short* wl[5];
};
__global__ __launch_bounds__(256) void prep_wb(PrepW p)
{
    const int z = blockIdx.z;
    const float* w = p.w[z];
    unsigned short* wh = p.wh[z];
    unsigned short* wl = p.wl[z];
    __shared__ float sW[32][36];
    const int t = threadIdx.x;
    const int n0 = blockIdx.x * 32, k0 = blockIdx.y * 32;
    {
        int kr = t >> 3, c4 = (t & 7) * 4;
        f32x4 v = *(const f32x4*)(w + (size_t)(k0 + kr) * 512 + n0 + c4);
        #pragma unroll
        for (int i = 0; i < 4; ++i) sW[kr][c4 + i] = v[i];
    }
    __syncthreads();
    {
        int nr = t >> 3, kc = (t & 7) * 4;
        u16x4 hv, lv;
        #pragma unroll
        for (int i = 0; i < 4; ++i) {
            float f = sW[kc + i][nr];
            unsigned short hb = f2bf(f);
            hv[i] = hb;
            lv[i] = f2bf(f - bf2f(hb));
        }
        *(u16x4*)(wh + (size_t)(n0 + nr) * 512 + k0 + kc) = hv;
        *(u16x4*)(wl + (size_t)(n0 + nr) * 512 + k0 + kc) = lv;
    }
}

// ---------------------------------------------------------------------------
// misc_k: blocks 0,1 -> bias_eff = b_ao @ w_o + b_o ; block 2 -> zero pb slack
// ---------------------------------------------------------------------------
__global__ __launch_bounds__(256) void misc_k(
    const float* __restrict__ b_ao, const float* __restrict__ w_o,
    const float* __restrict__ b_o, float* __restrict__ be,
    unsigned short* __restrict__ pb_base)
{
    if (blockIdx.x < 2) {
        int n = blockIdx.x * 256 + threadIdx.x;
        float s = b_o[n];
        for (int j = 0; j < 512; ++j) s += b_ao[j] * w_o[(size_t)j * 512 + n];
        be[n] = s;
    } else {
        ((unsigned int*)pb_base)[threadIdx.x] = 0u;
    }
}

// ---------------------------------------------------------------------------
// gemm_core: acc[MF][4] += A[M,512] @ W^T tile; split-bf16 (3 MFMAs).
// Tile = (MF*32) x 128, BK=32, 4 waves, global_load_lds + 4-slot XOR swizzle.
// ---------------------------------------------------------------------------
template<int MF>
__device__ __forceinline__ void gemm_core(
    f32x4 (&acc)[MF][4],
    const unsigned short* __restrict__ Ah_g,
    const unsigned short* __restrict__ Al_g, int lda,
    const unsigned short* __restrict__ Wh_g,
    const unsigned short* __restrict__ Wl_g,
    int M, int row0, int col0,
    unsigned short* sAh, unsigned short* sAl,
    unsigned short* sWh, unsigned short* sWl)
{
    const int t = threadIdx.x;
    const int lane = t & 63, w = t >> 6;
    const int wm = w >> 1, wn = w & 1;
    const int ln15 = lane & 15, g4 = lane >> 4;

    for (int kt = 0; kt < 16; ++kt) {
        __syncthreads();
        #pragma unroll
        for (int l = 0; l < MF / 2; ++l) {
            int e = l * 256 + w * 64 + lane;
            int row = e >> 2, slot = e & 3;
            int ss = slot ^ (row & 3);
            int gr = row0 + row;
            if (gr > M - 1) gr = M - 1;
            size_t ga = (size_t)gr * lda + kt * 32 + ss * 8;
            gload16(Ah_g + ga, sAh + (size_t)(l * 256 + w * 64) * 8);
            gload16(Al_g + ga, sAl + (size_t)(l * 256 + w * 64) * 8);
        }
        #pragma unroll
        for (int l = 0; l < 2; ++l) {
            int e = l * 256 + w * 64 + lane;
            int row = e >> 2, slot = e & 3;
            int ss = slot ^ (row & 3);
            size_t gw = (size_t)(col0 + row) * 512 + kt * 32 + ss * 8;
            gload16(Wh_g + gw, sWh + (size_t)(l * 256 + w * 64) * 8);
            gload16(Wl_g + gw, sWl + (size_t)(l * 256 + w * 64) * 8);
        }
        __syncthreads();

        bf16x8 fah[MF], fal[MF], fwh[4], fwl[4];
        #pragma unroll
        for (int i = 0; i < MF; ++i) {
            int ar = wm * (MF * 16) + i * 16 + ln15;
            int sa = (g4 ^ (ar & 3)) * 8;
            fah[i] = *(const bf16x8*)&sAh[ar * 32 + sa];
            fal[i] = *(const bf16x8*)&sAl[ar * 32 + sa];
        }
        #pragma unroll
        for (int j = 0; j < 4; ++j) {
            int wr = wn * 64 + j * 16 + ln15;
            int sw = (g4 ^ (wr & 3)) * 8;
            fwh[j] = *(const bf16x8*)&sWh[wr * 32 + sw];
            fwl[j] = *(const bf16x8*)&sWl[wr * 32 + sw];
        }
        __builtin_amdgcn_s_setprio(1);
        #pragma unroll
        for (int mi = 0; mi < MF; ++mi)
            #pragma unroll
            for (int ni = 0; ni < 4; ++ni) {
                acc[mi][ni] = mfma16(fah[mi], fwh[ni], acc[mi][ni]);
                acc[mi][ni] = mfma16(fah[mi], fwl[ni], acc[mi][ni]);
                acc[mi][ni] = mfma16(fal[mi], fwh[ni], acc[mi][ni]);
            }
        __builtin_amdgcn_s_setprio(0);
    }
}

#define GEMM_LDS(MF) \
    __shared__ __align__(16) unsigned short sAh[MF * 32 * 32]; \
    __shared__ __align__(16) unsigned short sAl[MF * 32 * 32]; \
    __shared__ __align__(16) unsigned short sWh[128 * 32];     \
    __shared__ __align__(16) unsigned short sWl[128 * 32];

// ---- fused QKV projection GEMM: N = 1536 (q|k|v), routed epilogue ----
__global__ __launch_bounds__(256, 3) void gemm_qkv(
    const unsigned short* __restrict__ Ah_g,
    const unsigned short* __restrict__ Al_g,
    const unsigned short* __restrict__ Wh_g,
    const unsigned short* __restrict__ Wl_g,
    const float* __restrict__ b_q, const float* __restrict__ bu,
    const float* __restrict__ bv, const float* __restrict__ b_k,
    const float* __restrict__ b_v,
    unsigned short* __restrict__ qu, unsigned short* __restrict__ qv,
    unsigned short* __restrict__ kb, unsigned short* __restrict__ vt)
{
    GEMM_LDS(4)
    f32x4 acc[4][4];
    #pragma unroll
    for (int i = 0; i < 4; ++i)
        #pragma unroll
        for (int j = 0; j < 4; ++j) acc[i][j] = (f32x4){0.f, 0.f, 0.f, 0.f};
    const int row0 = blockIdx.y * 128, col0 = blockIdx.x * 128;
    gemm_core<4>(acc, Ah_g, Al_g, 512, Wh_g, Wl_g, BT_, row0, col0,
                 sAh, sAl, sWh, sWl);

    const int t = threadIdx.x;
    const int lane = t & 63, w = t >> 6;
    const int wm = w >> 1, wn = w & 1;
    const int ln15 = lane & 15, g4 = lane >> 4;
    const int grp = col0 >> 9;   // 0=q, 1=k, 2=v (block-uniform)

    if (grp == 2) {
        #pragma unroll
        for (int mi = 0; mi < 4; ++mi) {
            int gr0 = row0 + wm * 64 + mi * 16 + g4 * 4;
            int bb = gr0 >> 10, t0 = gr0 & 1023;
            #pragma unroll
            for (int ni = 0; ni < 4; ++ni) {
                int gcl = (col0 & 511) + wn * 64 + ni * 16 + ln15;
                float bias = b_v[gcl];
                u16x4 vv;
                #pragma unroll
                for (int r4 = 0; r4 < 4; ++r4) vv[r4] = f2bf(acc[mi][ni][r4] + bias);
                *(u16x4*)(vt + ((size_t)(bb * 512 + gcl)) * 1024 + t0) = vv;
            }
        }
    } else {
        #pragma unroll
        for (int mi = 0; mi < 4; ++mi)
            #pragma unroll
            for (int r4 = 0; r4 < 4; ++r4) {
                int gr = row0 + wm * 64 + mi * 16 + g4 * 4 + r4;
                #pragma unroll
                for (int ni = 0; ni < 4; ++ni) {
                    int gcl = (col0 & 511) + wn * 64 + ni * 16 + ln15;
                    float a = acc[mi][ni][r4];
                    if (grp == 0) {
                        float base = a + b_q[gcl];
                        qu[(size_t)gr * 512 + gcl] = f2bf(base + bu[gcl]);
                        qv[(size_t)gr * 512 + gcl] = f2bf(base + bv[gcl]);
                    } else {
                        kb[(size_t)gr * 512 + gcl] = f2bf(a + b_k[gcl]);
                    }
                }
            }
    }
}

// ---- pos projection GEMM -> bf16 pb ----
__global__ __launch_bounds__(256, 3) void gemm_pos(
    const unsigned short* __restrict__ Ah_g,
    const unsigned short* __restrict__ Al_g,
    const unsigned short* __restrict__ Wh_g,
    const unsigned short* __restrict__ Wl_g,
    unsigned short* __restrict__ pb0)
{
    GEMM_LDS(4)
    f32x4 acc[4][4];
    #pragma unroll
    for (int i = 0; i < 4; ++i)
        #pragma unroll
        for (int j = 0; j < 4; ++j) acc[i][j] = (f32x4){0.f, 0.f, 0.f, 0.f};
    const int row0 = blockIdx.y * 128, col0 = blockIdx.x * 128;
    gemm_core<4>(acc, Ah_g, Al_g, 512, Wh_g, Wl_g, PLEN_, row0, col0,
                 sAh, sAl, sWh, sWl);

    const int t = threadIdx.x;
    const int lane = t & 63, w = t >> 6;
    const int wm = w >> 1, wn = w & 1;
    const int ln15 = lane & 15, g4 = lane >> 4;
    #pragma unroll
    for (int mi = 0; mi < 4; ++mi)
        #pragma unroll
        for (int r4 = 0; r4 < 4; ++r4) {
            int gr = row0 + wm * 64 + mi * 16 + g4 * 4 + r4;
            if (gr >= PLEN_) continue;
            #pragma unroll
            for (int ni = 0; ni < 4; ++ni) {
                int gc = col0 + wn * 64 + ni * 16 + ln15;
                pb0[(size_t)gr * 512 + gc] = f2bf(acc[mi][ni][r4]);
            }
        }
}

// ---- effective-weight GEMMs (batched, f32 out) ----
struct WeffA {
    const unsigned short* ah[4];
    const unsigned short* al[4];
    int lda[4];
    const unsigned short* wh[4];
    const unsigned short* wl[4];
    float* c[4];
};
__global__ __launch_bounds__(256, 3) void gemm_weff(WeffA a)
{
    GEMM_LDS(4)
    const int z = blockIdx.z;
    f32x4 acc[4][4];
    #pragma unroll
    for (int i = 0; i < 4; ++i)
        #pragma unroll
        for (int j = 0; j < 4; ++j) acc[i][j] = (f32x4){0.f, 0.f, 0.f, 0.f};
    const int row0 = blockIdx.y * 128, col0 = blockIdx.x * 128;
    gemm_core<4>(acc, a.ah[z], a.al[z], a.lda[z], a.wh[z], a.wl[z],
                 512, row0, col0, sAh, sAl, sWh, sWl);

    const int t = threadIdx.x;
    const int lane = t & 63, w = t >> 6;
    const int wm = w >> 1, wn = w & 1;
    const int ln15 = lane & 15, g4 = lane >> 4;
    float* C = a.c[z];
    #pragma unroll
    for (int mi = 0; mi < 4; ++mi)
        #pragma unroll
        for (int r4 = 0; r4 < 4; ++r4) {
            int gr = row0 + wm * 64 + mi * 16 + g4 * 4 + r4;
            #pragma unroll
            for (int ni = 0; ni < 4; ++ni) {
                int gc = col0 + wn * 64 + ni * 16 + ln15;
                C[(size_t)gr * 512 + gc] = acc[mi][ni][r4];
            }
        }
}

// ---- output GEMM: 64x128 tiles (more blocks -> latency hiding), f32 out ----
__global__ __launch_bounds__(256, 3) void gemm_out(
    const unsigned short* __restrict__ Ah_g,
    const unsigned short* __restrict__ Al_g,
    const unsigned short* __restrict__ Wh_g,
    const unsigned short* __restrict__ Wl_g,
    const float* __restrict__ beff, float* __restrict__ C)
{
    GEMM_LDS(2)
    f32x4 acc[2][4];
    #pragma unroll
    for (int i = 0; i < 2; ++i)
        #pragma unroll
        for (int j = 0; j < 4; ++j) acc[i][j] = (f32x4){0.f, 0.f, 0.f, 0.f};
    const int row0 = blockIdx.y * 64, col0 = blockIdx.x * 128;
    gemm_core<2>(acc, Ah_g, Al_g, 512, Wh_g, Wl_g, BT_, row0, col0,
                 sAh, sAl, sWh, sWl);

    const int t = threadIdx.x;
    const int lane = t & 63, w = t >> 6;
    const int wm = w >> 1, wn = w & 1;
    const int ln15 = lane & 15, g4 = lane >> 4;
    #pragma unroll
    for (int mi = 0; mi < 2; ++mi)
        #pragma unroll
        for (int r4 = 0; r4 < 4; ++r4) {
            int gr = row0 + wm * 32 + mi * 16 + g4 * 4 + r4;
            #pragma unroll
            for (int ni = 0; ni < 4; ++ni) {
                int gc = col0 + wn * 64 + ni * 16 + ln15;
                C[(size_t)gr * 512 + gc] = acc[mi][ni][r4] + beff[gc];
            }
        }
}

// ---------------------------------------------------------------------------
// attn_v2: swapped-operand flash rel-pos attention.
// Lane owns ONE q row (q = w*16 + ln15); k/d vary along acc regs.
// C[k,q] = mfma(K_frag, Qu_frag); ring gather is 4 consecutive cols;
// softmax row-reduce = 2 shuffles (xor 16/32); ring/sProb wave-private.
// LDS 51.2 KB -> 3 blocks/CU.
// ---------------------------------------------------------------------------
__global__ __launch_bounds__(256, 3) void attn_v2(
    const unsigned short* __restrict__ qu_g,
    const unsigned short* __restrict__ qv_g,
    const unsigned short* __restrict__ kb_g,
    const unsigned short* __restrict__ vt_g,
    const unsigned short* __restrict__ pb_g,   // p=0 (zeroed 512-slack before)
    unsigned short* __restrict__ atth,
    unsigned short* __restrict__ attl)
{
    __shared__ __align__(16) unsigned short sK[64 * 64];
    __shared__ __align__(16) unsigned short sP[64 * 64];
    __shared__ __align__(16) unsigned short sV[64 * 64];   // [d][token]
    __shared__ __align__(16) unsigned short ringb[64][136]; // bf16 BD ring +dup
    __shared__ __align__(16) unsigned short sProb[64][72];  // [q][k]

    const int t = threadIdx.x;
    const int lane = t & 63, w = t >> 6;
    const int ln15 = lane & 15, g4 = lane >> 4;

    // XCD-aware swizzle (1024 blocks, 8 XCDs, bijective)
    const int wg = blockIdx.x;
    const int idx = (wg & 7) * 128 + (wg >> 3);
    const int q0 = (idx & 15) * 64;
    const int bh = idx >> 4;
    const int h = bh & 7, b = bh >> 3;
    const size_t tok0 = (size_t)b * T_;
    const int hd = h * DK_;
    const int qq = w * 16 + ln15;           // this lane's local q row

    // ---- stage Qu -> sK, Qv -> sP ----
    #pragma unroll
    for (int l = 0; l < 2; ++l) {
        int e = l * 256 + w * 64 + lane;
        int row = e >> 3, slot = e & 7;
        int sl = slot ^ (row & 7);
        size_t src = (tok0 + q0 + row) * INNER_ + hd + sl * 8;
        gload16(qu_g + src, &sK[(size_t)(l * 256 + w * 64) * 8]);
        gload16(qv_g + src, &sP[(size_t)(l * 256 + w * 64) * 8]);
    }
    __syncthreads();
    bf16x8 fqu[2], fqv[2];
    #pragma unroll
    for (int ki = 0; ki < 2; ++ki) {
        int sl = (ki * 4 + g4) ^ (qq & 7);
        fqu[ki] = *(const bf16x8*)&sK[qq * 64 + sl * 8];
        fqv[ki] = *(const bf16x8*)&sP[qq * 64 + sl * 8];
    }
    __syncthreads();

    // ---- prologue: P rows p = 959 - q0 + r -> ring pos 0..63 ----
    #pragma unroll
    for (int l = 0; l < 2; ++l) {
        int e = l * 256 + w * 64 + lane;
        int row = e >> 3, slot = e & 7;
        int sl = slot ^ (row & 7);
        long p = (long)(959 - q0 + row);
        gload16(pb_g + p * INNER_ + hd + sl * 8, &sP[(size_t)(l * 256 + w * 64) * 8]);
    }
    __syncthreads();
    #pragma unroll
    for (int n = 0; n < 4; ++n) {
        f32x4 bd = {0.f, 0.f, 0.f, 0.f};
        #pragma unroll
        for (int ki = 0; ki < 2; ++ki) {
            int prow = n * 16 + ln15;
            int sl = (ki * 4 + g4) ^ (prow & 7);
            bf16x8 pf = *(const bf16x8*)&sP[prow * 64 + sl * 8];
            bd = mfma16(pf, fqv[ki], bd);
        }
        u16x4 rw;
        #pragma unroll
        for (int r4 = 0; r4 < 4; ++r4) rw[r4] = f2bf(bd[r4]);
        *(u16x4*)&ringb[qq][n * 16 + g4 * 4] = rw;
        if (n == 0 && g4 == 0) *(u16x4*)&ringb[qq][128] = rw;
    }

    float m = -INFINITY, den = 0.f;
    f32x4 o[4];
    #pragma unroll
    for (int i = 0; i < 4; ++i) o[i] = (f32x4){0.f, 0.f, 0.f, 0.f};

    for (int c = 0; c < 16; ++c) {
        __syncthreads();   // all waves done reading sK/sP/sV
        #pragma unroll
        for (int l = 0; l < 2; ++l) {
            int e = l * 256 + w * 64 + lane;
            int row = e >> 3, slot = e & 7;
            int sl = slot ^ (row & 7);
            int lofs = (l * 256 + w * 64) * 8;
            gload16(kb_g + (tok0 + c * 64 + row) * INNER_ + hd + sl * 8, &sK[lofs]);
            gload16(vt_g + ((size_t)(b * H_ + h) * DK_ + row) * T_ + c * 64 + sl * 8, &sV[lofs]);
            long p = (long)(c * 64 - q0 + 1023 + row);
            gload16(pb_g + p * INNER_ + hd + sl * 8, &sP[lofs]);
        }
        __syncthreads();   // staging complete (vmcnt drained by barrier)

        // AC + BD MFMAs (C[k,q] / C[p,q])
        f32x4 sc[4], bd[4];
        #pragma unroll
        for (int n = 0; n < 4; ++n) {
            sc[n] = (f32x4){0.f, 0.f, 0.f, 0.f};
            bd[n] = (f32x4){0.f, 0.f, 0.f, 0.f};
        }
        __builtin_amdgcn_s_setprio(1);
        #pragma unroll
        for (int ki = 0; ki < 2; ++ki)
            #pragma unroll
            for (int n = 0; n < 4; ++n) {
                int krow = n * 16 + ln15;
                int sl = (ki * 4 + g4) ^ (krow & 7);
                bf16x8 kf = *(const bf16x8*)&sK[krow * 64 + sl * 8];
                sc[n] = mfma16(kf, fqu[ki], sc[n]);
                bf16x8 pf = *(const bf16x8*)&sP[krow * 64 + sl * 8];
                bd[n] = mfma16(pf, fqv[ki], bd[n]);
            }
        __builtin_amdgcn_s_setprio(0);

        // ring write (wave-private rows)
        const int pbase = (c & 1) ? 0 : 64;
        #pragma unroll
        for (int n = 0; n < 4; ++n) {
            u16x4 rw;
            #pragma unroll
            for (int r4 = 0; r4 < 4; ++r4) rw[r4] = f2bf(bd[n][r4]);
            *(u16x4*)&ringb[qq][pbase + n * 16 + g4 * 4] = rw;
            if (pbase == 0 && n == 0 && g4 == 0) *(u16x4*)&ringb[qq][128] = rw;
        }

        // scores + online softmax (one q row per lane, 4 replicas)
        float s[4][4];
        const int base0 = c * 64 + 64 - qq;
        float mx = -1e30f;
        #pragma unroll
        for (int n = 0; n < 4; ++n) {
            int st = (base0 + n * 16 + g4 * 4) & 127;
            #pragma unroll
            for (int r4 = 0; r4 < 4; ++r4) {
                float v = (sc[n][r4] + bf2f(ringb[qq][st + r4])) * 0.125f;
                s[n][r4] = v;
                mx = fmaxf(mx, v);
            }
        }
        mx = fmaxf(mx, __shfl_xor(mx, 16));
        mx = fmaxf(mx, __shfl_xor(mx, 32));
        float newm = fmaxf(m, mx);
        float scale = __expf(m - newm);
        m = newm;
        float ls = 0.f;
        #pragma unroll
        for (int n = 0; n < 4; ++n) {
            u16x4 pv4;
            #pragma unroll
            for (int r4 = 0; r4 < 4; ++r4) {
                float p = __expf(s[n][r4] - newm);
                ls += p;
                pv4[r4] = f2bf(p);
            }
            *(u16x4*)&sProb[qq][n * 16 + g4 * 4] = pv4;
        }
        ls += __shfl_xor(ls, 16);
        ls += __shfl_xor(ls, 32);
        den = den * scale + ls;
        #pragma unroll
        for (int n2 = 0; n2 < 4; ++n2) {
            o[n2][0] *= scale; o[n2][1] *= scale;
            o[n2][2] *= scale; o[n2][3] *= scale;
        }

        // PV: O^T[d,q] += V[d,tok] @ P[tok,q]
        __builtin_amdgcn_s_setprio(1);
        #pragma unroll
        for (int ki = 0; ki < 2; ++ki) {
            bf16x8 pa = *(const bf16x8*)&sProb[qq][ki * 32 + g4 * 8];
            #pragma unroll
            for (int n2 = 0; n2 < 4; ++n2) {
                int drow = n2 * 16 + ln15;
                int sl = (ki * 4 + g4) ^ (drow & 7);
                bf16x8 vf = *(const bf16x8*)&sV[drow * 64 + sl * 8];
                o[n2] = mfma16(vf, pa, o[n2]);
            }
        }
        __builtin_amdgcn_s_setprio(0);
    }

    const float inv = 1.0f / den;
    #pragma unroll
    for (int n2 = 0; n2 < 4; ++n2) {
        u16x4 hv, lv;
        #pragma unroll
        for (int r4 = 0; r4 < 4; ++r4) {
            float val = o[n2][r4] * inv;
            unsigned short hb = f2bf(val);
            hv[r4] = hb;
            lv[r4] = f2bf(val - bf2f(hb));
        }
        size_t oidx = (tok0 + q0 + qq) * INNER_ + hd + n2 * 16 + g4 * 4;
        *(u16x4*)(atth + oidx) = hv;
        *(u16x4*)(attl + oidx) = lv;
    }
}

// ---------------------------------------------------------------------------
extern "C" void kernel_launch(void* const* d_in, const int* in_sizes, int n_in,
                              void* d_out, int out_size, void* d_ws, size_t ws_size,
                              hipStream_t stream)
{
    const float* x     = (const float*)d_in[0];
    const float* pos   = (const float*)d_in[1];
    const float* w_qkv = (const float*)d_in[2];
    const float* w_q   = (const float*)d_in[3];
    const float* b_q   = (const float*)d_in[4];
    const float* w_k   = (const float*)d_in[5];
    const float* b_k   = (const float*)d_in[6];
    const float* w_v   = (const float*)d_in[7];
    const float* b_v   = (const float*)d_in[8];
    const float* w_pos = (const float*)d_in[9];
    const float* bu    = (const float*)d_in[10];
    const float* bv    = (const float*)d_in[11];
    const float* w_ao  = (const float*)d_in[12];
    const float* b_ao  = (const float*)d_in[13];
    const float* w_o   = (const float*)d_in[14];
    const float* b_o   = (const float*)d_in[15];
    float* out = (float*)d_out;

    unsigned short* u = (unsigned short*)d_ws;
    const size_t SZ = (size_t)BT_ * INNER_;          // 4,194,304
    unsigned short* xh   = u;
    unsigned short* xl   = xh + SZ;
    unsigned short* qu   = xl + SZ;
    unsigned short* qv   = qu + SZ;
    unsigned short* kb   = qv + SZ;
    unsigned short* vt   = kb + SZ;
    unsigned short* atth = vt + SZ;
    unsigned short* attl = atth + SZ;
    unsigned short* pb_base = attl + SZ;             // 512 slack + 2047*512
    unsigned short* pb0  = pb_base + 512;
    unsigned short* posh = pb_base + 1049600;
    unsigned short* posl = posh + 1049600;
    unsigned short* wqkvh = posl + 1049600;
    unsigned short* wqkvl = wqkvh + 786432;
    unsigned short* waoh  = wqkvl + 786432;
    unsigned short* waol  = waoh + 262144;
    unsigned short* w5    = waol + 262144;   // wq,wk,wv,wo,wp (h,l)
    unsigned short* wq_h = w5;              unsigned short* wq_l = w5 + 262144;
    unsigned short* wk_h = w5 + 2*262144;   unsigned short* wk_l = w5 + 3*262144;
    unsigned short* wv_h = w5 + 4*262144;   unsigned short* wv_l = w5 + 5*262144;
    unsigned short* wo_h = w5 + 6*262144;   unsigned short* wo_l = w5 + 7*262144;
    unsigned short* wp_h = w5 + 8*262144;   unsigned short* wp_l = w5 + 9*262144;
    float* weffC = (float*)(w5 + 10*262144);           // 4 x 262144 f32
    // effective-weight bf16: [1536][512] concat (q,k,v) hi then lo; then w_o eff
    unsigned short* wcat_h = (unsigned short*)(weffC + 4*262144);
    unsigned short* wcat_l = wcat_h + 786432;
    unsigned short* woe_h  = wcat_l + 786432;
    unsigned short* woe_l  = woe_h + 262144;
    float* beff = (float*)(woe_l + 262144);

    dim3 blk(256);

    // 1) input/weight splits (one batched launch)
    SplitA sa;
    sa.s[0] = x;     sa.h[0] = xh;    sa.l[0] = xl;    sa.n[0] = (long)SZ;
    sa.s[1] = w_qkv; sa.h[1] = wqkvh; sa.l[1] = wqkvl; sa.n[1] = 786432L;
    sa.s[2] = w_ao;  sa.h[2] = waoh;  sa.l[2] = waol;  sa.n[2] = 262144L;
    sa.s[3] = pos;   sa.h[3] = posh;  sa.l[3] = posl;  sa.n[3] = (long)PLEN_ * 512;
    split4<<<dim3(4096, 4), blk, 0, stream>>>(sa);

    // 2) transpose+split the five raw 512x512 weights
    PrepW p5;
    p5.w[0] = w_q;   p5.wh[0] = wq_h; p5.wl[0] = wq_l;
    p5.w[1] = w_k;   p5.wh[1] = wk_h; p5.wl[1] = wk_l;
    p5.w[2] = w_v;   p5.wh[2] = wv_h; p5.wl[2] = wv_l;
    p5.w[3] = w_o;   p5.wh[3] = wo_h; p5.wl[3] = wo_l;
    p5.w[4] = w_pos; p5.wh[4] = wp_h; p5.wl[4] = wp_l;
    prep_wb<<<dim3(16, 16, 5), blk, 0, stream>>>(p5);

    // 3) effective weights: Wq/k/v_eff = Wqkv_slice @ W*, Wo_eff = Wao @ Wo
    WeffA wa;
    wa.ah[0] = wqkvh;        wa.al[0] = wqkvl;        wa.lda[0] = 1536;
    wa.ah[1] = wqkvh + 512;  wa.al[1] = wqkvl + 512;  wa.lda[1] = 1536;
    wa.ah[2] = wqkvh + 1024; wa.al[2] = wqkvl + 1024; wa.lda[2] = 1536;
    wa.ah[3] = waoh;         wa.al[3] = waol;         wa.lda[3] = 512;
    wa.wh[0] = wq_h; wa.wl[0] = wq_l;
    wa.wh[1] = wk_h; wa.wl[1] = wk_l;
    wa.wh[2] = wv_h; wa.wl[2] = wv_l;
    wa.wh[3] = wo_h; wa.wl[3] = wo_l;
    wa.c[0] = weffC;             wa.c[1] = weffC + 262144;
    wa.c[2] = weffC + 2*262144;  wa.c[3] = weffC + 3*262144;
    gemm_weff<<<dim3(4, 4, 4), blk, 0, stream>>>(wa);

    // 4) transpose+split effective weights (q|k|v concat + wo_eff)
    PrepW p4;
    p4.w[0] = weffC;            p4.wh[0] = wcat_h;            p4.wl[0] = wcat_l;
    p4.w[1] = weffC + 262144;   p4.wh[1] = wcat_h + 262144;   p4.wl[1] = wcat_l + 262144;
    p4.w[2] = weffC + 2*262144; p4.wh[2] = wcat_h + 2*262144; p4.wl[2] = wcat_l + 2*262144;
    p4.w[3] = weffC + 3*262144; p4.wh[3] = woe_h;             p4.wl[3] = woe_l;
    p4.w[4] = nullptr; p4.wh[4] = nullptr; p4.wl[4] = nullptr;
    prep_wb<<<dim3(16, 16, 4), blk, 0, stream>>>(p4);

    // 5) bias_eff + pb slack zero
    misc_k<<<3, blk, 0, stream>>>(b_ao, w_o, b_o, beff, pb_base);

    // 6) fused q/k/v projection + pos projection
    gemm_qkv<<<dim3(12, 64), blk, 0, stream>>>(xh, xl, wcat_h, wcat_l,
        b_q, bu, bv, b_k, b_v, qu, qv, kb, vt);
    gemm_pos<<<dim3(4, 16), blk, 0, stream>>>(posh, posl, wp_h, wp_l, pb0);

    // 7) attention
    attn_v2<<<1024, blk, 0, stream>>>(qu, qv, kb, vt, pb0, atth, attl);

    // 8) output GEMM
    gemm_out<<<dim3(4, 128), blk, 0, stream>>>(atth, attl, woe_h, woe_l, beff, out);
}

// Round 5
// 228.974 us; speedup vs baseline: 8.0719x; 1.0366x over previous
//
#include <hip/hip_runtime.h>
#include <hip/hip_bf16.h>
#include <math.h>

#define H_     8
#define DK_    64
#define INNER_ 512
#define B_     8
#define T_     1024
#define D_     512
#define PLEN_  2047
#define BT_    8192

typedef __attribute__((ext_vector_type(8))) short bf16x8;
typedef __attribute__((ext_vector_type(4))) float f32x4;
typedef __attribute__((ext_vector_type(4))) unsigned short u16x4;
typedef __attribute__((ext_vector_type(8))) unsigned short u16x8;

__device__ __forceinline__ unsigned short f2bf(float f) {
    unsigned u = __float_as_uint(f);
    u += 0x7fffu + ((u >> 16) & 1u);
    return (unsigned short)(u >> 16);
}
__device__ __forceinline__ float bf2f(unsigned short s) {
    return __uint_as_float(((unsigned)s) << 16);
}
__device__ __forceinline__ f32x4 mfma16(bf16x8 a, bf16x8 b, f32x4 c) {
    return __builtin_amdgcn_mfma_f32_16x16x32_bf16(a, b, c, 0, 0, 0);
}
__device__ __forceinline__ void gload16(const unsigned short* g, unsigned short* l) {
    __builtin_amdgcn_global_load_lds(
        (const __attribute__((address_space(1))) void*)g,
        (__attribute__((address_space(3))) void*)l,
        16, 0, 0);
}

// ---------------------------------------------------------------------------
// split4: batched f32 -> hi/lo bf16 split
// ---------------------------------------------------------------------------
struct SplitA {
    const float* s[4];
    unsigned short* h[4];
    unsigned short* l[4];
    long n[4];
};
__global__ __launch_bounds__(256) void split4(SplitA a)
{
    const int seg = blockIdx.y;
    long i4 = ((long)blockIdx.x * 256 + threadIdx.x) * 4;
    if (i4 >= a.n[seg]) return;
    f32x4 v = *(const f32x4*)(a.s[seg] + i4);
    u16x4 hh, ll;
    #pragma unroll
    for (int i = 0; i < 4; ++i) {
        unsigned short hb = f2bf(v[i]);
        hh[i] = hb;
        ll[i] = f2bf(v[i] - bf2f(hb));
    }
    *(u16x4*)(a.h[seg] + i4) = hh;
    *(u16x4*)(a.l[seg] + i4) = ll;
}

// ---------------------------------------------------------------------------
// prep_wb: batched  w[512][512] f32 -> wh/wl[n][k] bf16 (transpose + split)
// ---------------------------------------------------------------------------
struct PrepW {
    const float* w[5];
    unsigned short* wh[5];
    unsigned short* wl[5];
};
__global__ __launch_bounds__(256) void prep_wb(PrepW p)
{
    const int z = blockIdx.z;
    const float* w = p.w[z];
    unsigned short* wh = p.wh[z];
    unsigned short* wl = p.wl[z];
    __shared__ float sW[32][36];
    const int t = threadIdx.x;
    const int n0 = blockIdx.x * 32, k0 = blockIdx.y * 32;
    {
        int kr = t >> 3, c4 = (t & 7) * 4;
        f32x4 v = *(const f32x4*)(w + (size_t)(k0 + kr) * 512 + n0 + c4);
        #pragma unroll
        for (int i = 0; i < 4; ++i) sW[kr][c4 + i] = v[i];
    }
    __syncthreads();
    {
        int nr = t >> 3, kc = (t & 7) * 4;
        u16x4 hv, lv;
        #pragma unroll
        for (int i = 0; i < 4; ++i) {
            float f = sW[kc + i][nr];
            unsigned short hb = f2bf(f);
            hv[i] = hb;
            lv[i] = f2bf(f - bf2f(hb));
        }
        *(u16x4*)(wh + (size_t)(n0 + nr) * 512 + k0 + kc) = hv;
        *(u16x4*)(wl + (size_t)(n0 + nr) * 512 + k0 + kc) = lv;
    }
}

// ---------------------------------------------------------------------------
// misc_k: blocks 0,1 -> bias_eff = b_ao @ w_o + b_o ; block 2 -> zero pb slack
// ---------------------------------------------------------------------------
__global__ __launch_bounds__(256) void misc_k(
    const float* __restrict__ b_ao, const float* __restrict__ w_o,
    const float* __restrict__ b_o, float* __restrict__ be,
    unsigned short* __restrict__ pb_base)
{
    if (blockIdx.x < 2) {
        int n = blockIdx.x * 256 + threadIdx.x;
        float s = b_o[n];
        for (int j = 0; j < 512; ++j) s += b_ao[j] * w_o[(size_t)j * 512 + n];
        be[n] = s;
    } else {
        ((unsigned int*)pb_base)[threadIdx.x] = 0u;
    }
}

// ---------------------------------------------------------------------------
// gemm_core: 2-phase double-buffered pipeline (T3 minimum recipe).
// stage(kt+1, buf^1) issued BEFORE compute(kt, buf); one barrier per k-step.
// Tile = (MF*32) x 128, BK=32, 4 waves, global_load_lds + 4-slot XOR swizzle.
// Split product: Ah*Wh + Ah*Wl + Al*Wh (3 MFMAs) ~= f32 accuracy.
// ---------------------------------------------------------------------------
template<int MF>
__device__ __forceinline__ void gemm_core(
    f32x4 (&acc)[MF][4],
    const unsigned short* __restrict__ Ah_g,
    const unsigned short* __restrict__ Al_g, int lda,
    const unsigned short* __restrict__ Wh_g,
    const unsigned short* __restrict__ Wl_g,
    int M, int row0, int col0,
    unsigned short* sAh, unsigned short* sAl,
    unsigned short* sWh, unsigned short* sWl)
{
    const int t = threadIdx.x;
    const int lane = t & 63, w = t >> 6;
    const int wm = w >> 1, wn = w & 1;
    const int ln15 = lane & 15, g4 = lane >> 4;
    const int ASZ = MF * 32 * 32;
    const int WSZ = 128 * 32;

    auto stage = [&](int kt, int buf) {
        #pragma unroll
        for (int l = 0; l < MF / 2; ++l) {
            int e = l * 256 + w * 64 + lane;
            int row = e >> 2, slot = e & 3;
            int ss = slot ^ (row & 3);
            int gr = row0 + row;
            if (gr > M - 1) gr = M - 1;
            size_t ga = (size_t)gr * lda + kt * 32 + ss * 8;
            gload16(Ah_g + ga, sAh + buf * ASZ + (l * 256 + w * 64) * 8);
            gload16(Al_g + ga, sAl + buf * ASZ + (l * 256 + w * 64) * 8);
        }
        #pragma unroll
        for (int l = 0; l < 2; ++l) {
            int e = l * 256 + w * 64 + lane;
            int row = e >> 2, slot = e & 3;
            int ss = slot ^ (row & 3);
            size_t gw = (size_t)(col0 + row) * 512 + kt * 32 + ss * 8;
            gload16(Wh_g + gw, sWh + buf * WSZ + (l * 256 + w * 64) * 8);
            gload16(Wl_g + gw, sWl + buf * WSZ + (l * 256 + w * 64) * 8);
        }
    };
    auto comp = [&](int buf) {
        bf16x8 fah[MF], fal[MF], fwh[4], fwl[4];
        #pragma unroll
        for (int i = 0; i < MF; ++i) {
            int ar = wm * (MF * 16) + i * 16 + ln15;
            int sa = (g4 ^ (ar & 3)) * 8;
            fah[i] = *(const bf16x8*)&sAh[buf * ASZ + ar * 32 + sa];
            fal[i] = *(const bf16x8*)&sAl[buf * ASZ + ar * 32 + sa];
        }
        #pragma unroll
        for (int j = 0; j < 4; ++j) {
            int wr = wn * 64 + j * 16 + ln15;
            int sw = (g4 ^ (wr & 3)) * 8;
            fwh[j] = *(const bf16x8*)&sWh[buf * WSZ + wr * 32 + sw];
            fwl[j] = *(const bf16x8*)&sWl[buf * WSZ + wr * 32 + sw];
        }
        __builtin_amdgcn_s_setprio(1);
        #pragma unroll
        for (int mi = 0; mi < MF; ++mi)
            #pragma unroll
            for (int ni = 0; ni < 4; ++ni) {
                acc[mi][ni] = mfma16(fah[mi], fwh[ni], acc[mi][ni]);
                acc[mi][ni] = mfma16(fah[mi], fwl[ni], acc[mi][ni]);
                acc[mi][ni] = mfma16(fal[mi], fwh[ni], acc[mi][ni]);
            }
        __builtin_amdgcn_s_setprio(0);
    };

    stage(0, 0);
    __syncthreads();
    for (int k2 = 0; k2 < 8; ++k2) {
        stage(2 * k2 + 1, 1);
        comp(0);
        __syncthreads();
        if (k2 < 7) stage(2 * k2 + 2, 0);
        comp(1);
        __syncthreads();
    }
}

#define GEMM_LDS(MF) \
    __shared__ __align__(16) unsigned short sAh[2][MF * 32 * 32]; \
    __shared__ __align__(16) unsigned short sAl[2][MF * 32 * 32]; \
    __shared__ __align__(16) unsigned short sWh[2][128 * 32];     \
    __shared__ __align__(16) unsigned short sWl[2][128 * 32];

// ---- fused QKV projection GEMM: N = 1536 (q|k|v), routed epilogue ----
__global__ __launch_bounds__(256, 2) void gemm_qkv(
    const unsigned short* __restrict__ Ah_g,
    const unsigned short* __restrict__ Al_g,
    const unsigned short* __restrict__ Wh_g,
    const unsigned short* __restrict__ Wl_g,
    const float* __restrict__ b_q, const float* __restrict__ bu,
    const float* __restrict__ bv, const float* __restrict__ b_k,
    const float* __restrict__ b_v,
    unsigned short* __restrict__ qu, unsigned short* __restrict__ qv,
    unsigned short* __restrict__ kb, unsigned short* __restrict__ vt)
{
    GEMM_LDS(4)
    f32x4 acc[4][4];
    #pragma unroll
    for (int i = 0; i < 4; ++i)
        #pragma unroll
        for (int j = 0; j < 4; ++j) acc[i][j] = (f32x4){0.f, 0.f, 0.f, 0.f};
    const int row0 = blockIdx.y * 128, col0 = blockIdx.x * 128;
    gemm_core<4>(acc, Ah_g, Al_g, 512, Wh_g, Wl_g, BT_, row0, col0,
                 &sAh[0][0], &sAl[0][0], &sWh[0][0], &sWl[0][0]);

    const int t = threadIdx.x;
    const int lane = t & 63, w = t >> 6;
    const int wm = w >> 1, wn = w & 1;
    const int ln15 = lane & 15, g4 = lane >> 4;
    const int grp = col0 >> 9;   // 0=q, 1=k, 2=v (block-uniform)

    if (grp == 2) {
        #pragma unroll
        for (int mi = 0; mi < 4; ++mi) {
            int gr0 = row0 + wm * 64 + mi * 16 + g4 * 4;
            int bb = gr0 >> 10, t0 = gr0 & 1023;
            #pragma unroll
            for (int ni = 0; ni < 4; ++ni) {
                int gcl = (col0 & 511) + wn * 64 + ni * 16 + ln15;
                float bias = b_v[gcl];
                u16x4 vv;
                #pragma unroll
                for (int r4 = 0; r4 < 4; ++r4) vv[r4] = f2bf(acc[mi][ni][r4] + bias);
                *(u16x4*)(vt + ((size_t)(bb * 512 + gcl)) * 1024 + t0) = vv;
            }
        }
    } else {
        #pragma unroll
        for (int mi = 0; mi < 4; ++mi)
            #pragma unroll
            for (int r4 = 0; r4 < 4; ++r4) {
                int gr = row0 + wm * 64 + mi * 16 + g4 * 4 + r4;
                #pragma unroll
                for (int ni = 0; ni < 4; ++ni) {
                    int gcl = (col0 & 511) + wn * 64 + ni * 16 + ln15;
                    float a = acc[mi][ni][r4];
                    if (grp == 0) {
                        // fold softmax 1/sqrt(dk)=0.125 here (exact pow2 scale)
                        float base = a + b_q[gcl];
                        qu[(size_t)gr * 512 + gcl] = f2bf((base + bu[gcl]) * 0.125f);
                        qv[(size_t)gr * 512 + gcl] = f2bf((base + bv[gcl]) * 0.125f);
                    } else {
                        kb[(size_t)gr * 512 + gcl] = f2bf(a + b_k[gcl]);
                    }
                }
            }
    }
}

// ---- pos projection GEMM -> bf16 pb ----
__global__ __launch_bounds__(256, 2) void gemm_pos(
    const unsigned short* __restrict__ Ah_g,
    const unsigned short* __restrict__ Al_g,
    const unsigned short* __restrict__ Wh_g,
    const unsigned short* __restrict__ Wl_g,
    unsigned short* __restrict__ pb0)
{
    GEMM_LDS(4)
    f32x4 acc[4][4];
    #pragma unroll
    for (int i = 0; i < 4; ++i)
        #pragma unroll
        for (int j = 0; j < 4; ++j) acc[i][j] = (f32x4){0.f, 0.f, 0.f, 0.f};
    const int row0 = blockIdx.y * 128, col0 = blockIdx.x * 128;
    gemm_core<4>(acc, Ah_g, Al_g, 512, Wh_g, Wl_g, PLEN_, row0, col0,
                 &sAh[0][0], &sAl[0][0], &sWh[0][0], &sWl[0][0]);

    const int t = threadIdx.x;
    const int lane = t & 63, w = t >> 6;
    const int wm = w >> 1, wn = w & 1;
    const int ln15 = lane & 15, g4 = lane >> 4;
    #pragma unroll
    for (int mi = 0; mi < 4; ++mi)
        #pragma unroll
        for (int r4 = 0; r4 < 4; ++r4) {
            int gr = row0 + wm * 64 + mi * 16 + g4 * 4 + r4;
            if (gr >= PLEN_) continue;
            #pragma unroll
            for (int ni = 0; ni < 4; ++ni) {
                int gc = col0 + wn * 64 + ni * 16 + ln15;
                pb0[(size_t)gr * 512 + gc] = f2bf(acc[mi][ni][r4]);
            }
        }
}

// ---- effective-weight GEMMs (batched, f32 out) ----
struct WeffA {
    const unsigned short* ah[4];
    const unsigned short* al[4];
    int lda[4];
    const unsigned short* wh[4];
    const unsigned short* wl[4];
    float* c[4];
};
__global__ __launch_bounds__(256, 2) void gemm_weff(WeffA a)
{
    GEMM_LDS(4)
    const int z = blockIdx.z;
    f32x4 acc[4][4];
    #pragma unroll
    for (int i = 0; i < 4; ++i)
        #pragma unroll
        for (int j = 0; j < 4; ++j) acc[i][j] = (f32x4){0.f, 0.f, 0.f, 0.f};
    const int row0 = blockIdx.y * 128, col0 = blockIdx.x * 128;
    gemm_core<4>(acc, a.ah[z], a.al[z], a.lda[z], a.wh[z], a.wl[z],
                 512, row0, col0, &sAh[0][0], &sAl[0][0], &sWh[0][0], &sWl[0][0]);

    const int t = threadIdx.x;
    const int lane = t & 63, w = t >> 6;
    const int wm = w >> 1, wn = w & 1;
    const int ln15 = lane & 15, g4 = lane >> 4;
    float* C = a.c[z];
    #pragma unroll
    for (int mi = 0; mi < 4; ++mi)
        #pragma unroll
        for (int r4 = 0; r4 < 4; ++r4) {
            int gr = row0 + wm * 64 + mi * 16 + g4 * 4 + r4;
            #pragma unroll
            for (int ni = 0; ni < 4; ++ni) {
                int gc = col0 + wn * 64 + ni * 16 + ln15;
                C[(size_t)gr * 512 + gc] = acc[mi][ni][r4];
            }
        }
}

// ---- output GEMM: 64x128 tiles, f32 out ----
__global__ __launch_bounds__(256, 3) void gemm_out(
    const unsigned short* __restrict__ Ah_g,
    const unsigned short* __restrict__ Al_g,
    const unsigned short* __restrict__ Wh_g,
    const unsigned short* __restrict__ Wl_g,
    const float* __restrict__ beff, float* __restrict__ C)
{
    GEMM_LDS(2)
    f32x4 acc[2][4];
    #pragma unroll
    for (int i = 0; i < 2; ++i)
        #pragma unroll
        for (int j = 0; j < 4; ++j) acc[i][j] = (f32x4){0.f, 0.f, 0.f, 0.f};
    const int row0 = blockIdx.y * 64, col0 = blockIdx.x * 128;
    gemm_core<2>(acc, Ah_g, Al_g, 512, Wh_g, Wl_g, BT_, row0, col0,
                 &sAh[0][0], &sAl[0][0], &sWh[0][0], &sWl[0][0]);

    const int t = threadIdx.x;
    const int lane = t & 63, w = t >> 6;
    const int wm = w >> 1, wn = w & 1;
    const int ln15 = lane & 15, g4 = lane >> 4;
    #pragma unroll
    for (int mi = 0; mi < 2; ++mi)
        #pragma unroll
        for (int r4 = 0; r4 < 4; ++r4) {
            int gr = row0 + wm * 32 + mi * 16 + g4 * 4 + r4;
            #pragma unroll
            for (int ni = 0; ni < 4; ++ni) {
                int gc = col0 + wn * 64 + ni * 16 + ln15;
                C[(size_t)gr * 512 + gc] = acc[mi][ni][r4] + beff[gc];
            }
        }
}

// ---------------------------------------------------------------------------
// attn_v3: swapped-operand flash rel-pos attention, 2-phase pipelined staging.
// Lane owns ONE q row (qq = w*16 + ln15). Double-buffered K/V/P; prefetch of
// chunk c+1 issued before compute of chunk c; ONE barrier per chunk.
// BD ring rotated by qq: reads are 4-aligned u16x4 vector reads.
// ---------------------------------------------------------------------------
__global__ __launch_bounds__(256, 2) void attn_v3(
    const unsigned short* __restrict__ qu_g,
    const unsigned short* __restrict__ qv_g,
    const unsigned short* __restrict__ kb_g,
    const unsigned short* __restrict__ vt_g,
    const unsigned short* __restrict__ pb_g,   // p=0 (zeroed 512-slack before)
    unsigned short* __restrict__ atth,
    unsigned short* __restrict__ attl)
{
    __shared__ __align__(16) unsigned short sK[2][64 * 64];
    __shared__ __align__(16) unsigned short sP[2][64 * 64];
    __shared__ __align__(16) unsigned short sV[2][64 * 64];   // [d][token]
    __shared__ __align__(16) unsigned short ringb[64][132];   // rotated bf16 ring
    __shared__ __align__(16) unsigned short sProb[64][72];    // [q][k]

    const int t = threadIdx.x;
    const int lane = t & 63, w = t >> 6;
    const int ln15 = lane & 15, g4 = lane >> 4;

    // XCD-aware swizzle (1024 blocks, 8 XCDs, bijective)
    const int wg = blockIdx.x;
    const int idx = (wg & 7) * 128 + (wg >> 3);
    const int q0 = (idx & 15) * 64;
    const int bh = idx >> 4;
    const int h = bh & 7, b = bh >> 3;
    const size_t tok0 = (size_t)b * T_;
    const int hd = h * DK_;
    const int qq = w * 16 + ln15;           // this lane's q row

    auto stage_chunk = [&](int c, int buf) {
        #pragma unroll
        for (int l = 0; l < 2; ++l) {
            int e = l * 256 + w * 64 + lane;
            int row = e >> 3, slot = e & 7;
            int sl = slot ^ (row & 7);
            int lofs = buf * 4096 + (l * 256 + w * 64) * 8;
            gload16(kb_g + (tok0 + c * 64 + row) * INNER_ + hd + sl * 8, &sK[0][lofs]);
            gload16(vt_g + ((size_t)(b * H_ + h) * DK_ + row) * T_ + c * 64 + sl * 8, &sV[0][lofs]);
            long p = (long)(c * 64 - q0 + 1023 + row);
            gload16(pb_g + p * INNER_ + hd + sl * 8, &sP[0][lofs]);
        }
    };

    // ---- stage Qu -> sK[0], Qv -> sP[0]; pull fragments ----
    #pragma unroll
    for (int l = 0; l < 2; ++l) {
        int e = l * 256 + w * 64 + lane;
        int row = e >> 3, slot = e & 7;
        int sl = slot ^ (row & 7);
        size_t src = (tok0 + q0 + row) * INNER_ + hd + sl * 8;
        gload16(qu_g + src, &sK[0][(l * 256 + w * 64) * 8]);
        gload16(qv_g + src, &sP[0][(l * 256 + w * 64) * 8]);
    }
    __syncthreads();
    bf16x8 fqu[2], fqv[2];
    #pragma unroll
    for (int ki = 0; ki < 2; ++ki) {
        int sl = (ki * 4 + g4) ^ (qq & 7);
        fqu[ki] = *(const bf16x8*)&sK[0][qq * 64 + sl * 8];
        fqv[ki] = *(const bf16x8*)&sP[0][qq * 64 + sl * 8];
    }
    __syncthreads();

    // ---- stage prologue-P window -> sP[1] AND chunk0 -> buf0 ----
    #pragma unroll
    for (int l = 0; l < 2; ++l) {
        int e = l * 256 + w * 64 + lane;
        int row = e >> 3, slot = e & 7;
        int sl = slot ^ (row & 7);
        long p = (long)(959 - q0 + row);
        gload16(pb_g + p * INNER_ + hd + sl * 8, &sP[1][(l * 256 + w * 64) * 8]);
    }
    stage_chunk(0, 0);
    __syncthreads();

    // ---- ring prologue (window rows -> ring pos 0..63, rotated by qq) ----
    #pragma unroll
    for (int n = 0; n < 4; ++n) {
        f32x4 bdv = {0.f, 0.f, 0.f, 0.f};
        #pragma unroll
        for (int ki = 0; ki < 2; ++ki) {
            int prow = n * 16 + ln15;
            int sl = (ki * 4 + g4) ^ (prow & 7);
            bf16x8 pf = *(const bf16x8*)&sP[1][prow * 64 + sl * 8];
            bdv = mfma16(pf, fqv[ki], bdv);
        }
        #pragma unroll
        for (int r4 = 0; r4 < 4; ++r4)
            ringb[qq][(n * 16 + g4 * 4 + r4 + qq) & 127] = f2bf(bdv[r4]);
    }
    __syncthreads();   // sP[1] free for chunk-1 prefetch

    float m = -INFINITY, den = 0.f;
    f32x4 o[4];
    #pragma unroll
    for (int i = 0; i < 4; ++i) o[i] = (f32x4){0.f, 0.f, 0.f, 0.f};

    auto compute_chunk = [&](int c, int buf) {
        const int bofs = buf * 4096;
        f32x4 sc[4], bd[4];
        #pragma unroll
        for (int n = 0; n < 4; ++n) {
            sc[n] = (f32x4){0.f, 0.f, 0.f, 0.f};
            bd[n] = (f32x4){0.f, 0.f, 0.f, 0.f};
        }
        __builtin_amdgcn_s_setprio(1);
        #pragma unroll
        for (int ki = 0; ki < 2; ++ki)
            #pragma unroll
            for (int n = 0; n < 4; ++n) {
                int krow = n * 16 + ln15;
                int sl = (ki * 4 + g4) ^ (krow & 7);
                bf16x8 kf = *(const bf16x8*)&sK[0][bofs + krow * 64 + sl * 8];
                sc[n] = mfma16(kf, fqu[ki], sc[n]);
                bf16x8 pf = *(const bf16x8*)&sP[0][bofs + krow * 64 + sl * 8];
                bd[n] = mfma16(pf, fqv[ki], bd[n]);
            }
        __builtin_amdgcn_s_setprio(0);

        // ring write (rotated; wave-private rows; off critical path)
        const int pbase = (c & 1) ? 0 : 64;
        #pragma unroll
        for (int n = 0; n < 4; ++n)
            #pragma unroll
            for (int r4 = 0; r4 < 4; ++r4)
                ringb[qq][(pbase + n * 16 + g4 * 4 + r4 + qq) & 127] = f2bf(bd[n][r4]);

        // scores + online softmax (scale pre-folded into qu/qv)
        float s[4][4];
        float mx = -1e30f;
        #pragma unroll
        for (int n = 0; n < 4; ++n) {
            const int st2 = (c * 64 + 64 + n * 16 + g4 * 4) & 127;  // 4-aligned
            u16x4 rv = *(const u16x4*)&ringb[qq][st2];
            #pragma unroll
            for (int r4 = 0; r4 < 4; ++r4) {
                float v = sc[n][r4] + bf2f(rv[r4]);
                s[n][r4] = v;
                mx = fmaxf(mx, v);
            }
        }
        mx = fmaxf(mx, __shfl_xor(mx, 16));
        mx = fmaxf(mx, __shfl_xor(mx, 32));
        float newm = fmaxf(m, mx);
        float scale = __expf(m - newm);
        m = newm;
        float ls = 0.f;
        #pragma unroll
        for (int n = 0; n < 4; ++n) {
            u16x4 pv4;
            #pragma unroll
            for (int r4 = 0; r4 < 4; ++r4) {
                float p = __expf(s[n][r4] - newm);
                ls += p;
                pv4[r4] = f2bf(p);
            }
            *(u16x4*)&sProb[qq][n * 16 + g4 * 4] = pv4;
        }
        ls += __shfl_xor(ls, 16);
        ls += __shfl_xor(ls, 32);
        den = den * scale + ls;
        #pragma unroll
        for (int n2 = 0; n2 < 4; ++n2) {
            o[n2][0] *= scale; o[n2][1] *= scale;
            o[n2][2] *= scale; o[n2][3] *= scale;
        }

        // PV: O^T[d,q] += V[d,tok] @ P[tok,q]
        __builtin_amdgcn_s_setprio(1);
        #pragma unroll
        for (int ki = 0; ki < 2; ++ki) {
            bf16x8 pa = *(const bf16x8*)&sProb[qq][ki * 32 + g4 * 8];
            #pragma unroll
            for (int n2 = 0; n2 < 4; ++n2) {
                int drow = n2 * 16 + ln15;
                int sl = (ki * 4 + g4) ^ (drow & 7);
                bf16x8 vf = *(const bf16x8*)&sV[0][bofs + drow * 64 + sl * 8];
                o[n2] = mfma16(vf, pa, o[n2]);
            }
        }
        __builtin_amdgcn_s_setprio(0);
    };

    // ---- main 2-phase pipelined loop: stage(c+1) -> compute(c) -> barrier ----
    for (int c2 = 0; c2 < 8; ++c2) {
        int c = c2 * 2;
        stage_chunk(c + 1, 1);
        compute_chunk(c, 0);
        __syncthreads();
        if (c2 < 7) stage_chunk(c + 2, 0);
        compute_chunk(c + 1, 1);
        __syncthreads();
    }

    const float inv = 1.0f / den;
    #pragma unroll
    for (int n2 = 0; n2 < 4; ++n2) {
        u16x4 hv, lv;
        #pragma unroll
        for (int r4 = 0; r4 < 4; ++r4) {
            float val = o[n2][r4] * inv;
            unsigned short hb = f2bf(val);
            hv[r4] = hb;
            lv[r4] = f2bf(val - bf2f(hb));
        }
        size_t oidx = (tok0 + q0 + qq) * INNER_ + hd + n2 * 16 + g4 * 4;
        *(u16x4*)(atth + oidx) = hv;
        *(u16x4*)(attl + oidx) = lv;
    }
}

// ---------------------------------------------------------------------------
extern "C" void kernel_launch(void* const* d_in, const int* in_sizes, int n_in,
                              void* d_out, int out_size, void* d_ws, size_t ws_size,
                              hipStream_t stream)
{
    const float* x     = (const float*)d_in[0];
    const float* pos   = (const float*)d_in[1];
    const float* w_qkv = (const float*)d_in[2];
    const float* w_q   = (const float*)d_in[3];
    const float* b_q   = (const float*)d_in[4];
    const float* w_k   = (const float*)d_in[5];
    const float* b_k   = (const float*)d_in[6];
    const float* w_v   = (const float*)d_in[7];
    const float* b_v   = (const float*)d_in[8];
    const float* w_pos = (const float*)d_in[9];
    const float* bu    = (const float*)d_in[10];
    const float* bv    = (const float*)d_in[11];
    const float* w_ao  = (const float*)d_in[12];
    const float* b_ao  = (const float*)d_in[13];
    const float* w_o   = (const float*)d_in[14];
    const float* b_o   = (const float*)d_in[15];
    float* out = (float*)d_out;

    unsigned short* u = (unsigned short*)d_ws;
    const size_t SZ = (size_t)BT_ * INNER_;          // 4,194,304
    unsigned short* xh   = u;
    unsigned short* xl   = xh + SZ;
    unsigned short* qu   = xl + SZ;
    unsigned short* qv   = qu + SZ;
    unsigned short* kb   = qv + SZ;
    unsigned short* vt   = kb + SZ;
    unsigned short* atth = vt + SZ;
    unsigned short* attl = atth + SZ;
    unsigned short* pb_base = attl + SZ;             // 512 slack + 2047*512
    unsigned short* pb0  = pb_base + 512;
    unsigned short* posh = pb_base + 1049600;
    unsigned short* posl = posh + 1049600;
    unsigned short* wqkvh = posl + 1049600;
    unsigned short* wqkvl = wqkvh + 786432;
    unsigned short* waoh  = wqkvl + 786432;
    unsigned short* waol  = waoh + 262144;
    unsigned short* w5    = waol + 262144;   // wq,wk,wv,wo,wp (h,l)
    unsigned short* wq_h = w5;              unsigned short* wq_l = w5 + 262144;
    unsigned short* wk_h = w5 + 2*262144;   unsigned short* wk_l = w5 + 3*262144;
    unsigned short* wv_h = w5 + 4*262144;   unsigned short* wv_l = w5 + 5*262144;
    unsigned short* wo_h = w5 + 6*262144;   unsigned short* wo_l = w5 + 7*262144;
    unsigned short* wp_h = w5 + 8*262144;   unsigned short* wp_l = w5 + 9*262144;
    float* weffC = (float*)(w5 + 10*262144);           // 4 x 262144 f32
    unsigned short* wcat_h = (unsigned short*)(weffC + 4*262144);
    unsigned short* wcat_l = wcat_h + 786432;
    unsigned short* woe_h  = wcat_l + 786432;
    unsigned short* woe_l  = woe_h + 262144;
    float* beff = (float*)(woe_l + 262144);

    dim3 blk(256);

    // 1) input/weight splits (one batched launch)
    SplitA sa;
    sa.s[0] = x;     sa.h[0] = xh;    sa.l[0] = xl;    sa.n[0] = (long)SZ;
    sa.s[1] = w_qkv; sa.h[1] = wqkvh; sa.l[1] = wqkvl; sa.n[1] = 786432L;
    sa.s[2] = w_ao;  sa.h[2] = waoh;  sa.l[2] = waol;  sa.n[2] = 262144L;
    sa.s[3] = pos;   sa.h[3] = posh;  sa.l[3] = posl;  sa.n[3] = (long)PLEN_ * 512;
    split4<<<dim3(4096, 4), blk, 0, stream>>>(sa);

    // 2) transpose+split the five raw 512x512 weights
    PrepW p5;
    p5.w[0] = w_q;   p5.wh[0] = wq_h; p5.wl[0] = wq_l;
    p5.w[1] = w_k;   p5.wh[1] = wk_h; p5.wl[1] = wk_l;
    p5.w[2] = w_v;   p5.wh[2] = wv_h; p5.wl[2] = wv_l;
    p5.w[3] = w_o;   p5.wh[3] = wo_h; p5.wl[3] = wo_l;
    p5.w[4] = w_pos; p5.wh[4] = wp_h; p5.wl[4] = wp_l;
    prep_wb<<<dim3(16, 16, 5), blk, 0, stream>>>(p5);

    // 3) effective weights: Wq/k/v_eff = Wqkv_slice @ W*, Wo_eff = Wao @ Wo
    WeffA wa;
    wa.ah[0] = wqkvh;        wa.al[0] = wqkvl;        wa.lda[0] = 1536;
    wa.ah[1] = wqkvh + 512;  wa.al[1] = wqkvl + 512;  wa.lda[1] = 1536;
    wa.ah[2] = wqkvh + 1024; wa.al[2] = wqkvl + 1024; wa.lda[2] = 1536;
    wa.ah[3] = waoh;         wa.al[3] = waol;         wa.lda[3] = 512;
    wa.wh[0] = wq_h; wa.wl[0] = wq_l;
    wa.wh[1] = wk_h; wa.wl[1] = wk_l;
    wa.wh[2] = wv_h; wa.wl[2] = wv_l;
    wa.wh[3] = wo_h; wa.wl[3] = wo_l;
    wa.c[0] = weffC;             wa.c[1] = weffC + 262144;
    wa.c[2] = weffC + 2*262144;  wa.c[3] = weffC + 3*262144;
    gemm_weff<<<dim3(4, 4, 4), blk, 0, stream>>>(wa);

    // 4) transpose+split effective weights (q|k|v concat + wo_eff)
    PrepW p4;
    p4.w[0] = weffC;            p4.wh[0] = wcat_h;            p4.wl[0] = wcat_l;
    p4.w[1] = weffC + 262144;   p4.wh[1] = wcat_h + 262144;   p4.wl[1] = wcat_l + 262144;
    p4.w[2] = weffC + 2*262144; p4.wh[2] = wcat_h + 2*262144; p4.wl[2] = wcat_l + 2*262144;
    p4.w[3] = weffC + 3*262144; p4.wh[3] = woe_h;             p4.wl[3] = woe_l;
    p4.w[4] = nullptr; p4.wh[4] = nullptr; p4.wl[4] = nullptr;
    prep_wb<<<dim3(16, 16, 4), blk, 0, stream>>>(p4);

    // 5) bias_eff + pb slack zero
    misc_k<<<3, blk, 0, stream>>>(b_ao, w_o, b_o, beff, pb_base);

    // 6) fused q/k/v projection + pos projection
    gemm_qkv<<<dim3(12, 64), blk, 0, stream>>>(xh, xl, wcat_h, wcat_l,
        b_q, bu, bv, b_k, b_v, qu, qv, kb, vt);
    gemm_pos<<<dim3(4, 16), blk, 0, stream>>>(posh, posl, wp_h, wp_l, pb0);

    // 7) attention
    attn_v3<<<1024, blk, 0, stream>>>(qu, qv, kb, vt, pb0, atth, attl);

    // 8) output GEMM
    gemm_out<<<dim3(4, 128), blk, 0, stream>>>(atth, attl, woe_h, woe_l, beff, out);
}

// Round 8
// 228.136 us; speedup vs baseline: 8.1016x; 1.0037x over previous
//
#include <hip/hip_runtime.h>
#include <hip/hip_bf16.h>
#include <math.h>

#define H_     8
#define DK_    64
#define INNER_ 512
#define B_     8
#define T_     1024
#define D_     512
#define PLEN_  2047
#define BT_    8192

typedef __attribute__((ext_vector_type(8))) short bf16x8;
typedef __attribute__((ext_vector_type(4))) float f32x4;
typedef __attribute__((ext_vector_type(4))) unsigned short u16x4;
typedef __attribute__((ext_vector_type(8))) unsigned short u16x8;

__device__ __forceinline__ unsigned short f2bf(float f) {
    unsigned u = __float_as_uint(f);
    u += 0x7fffu + ((u >> 16) & 1u);
    return (unsigned short)(u >> 16);
}
__device__ __forceinline__ float bf2f(unsigned short s) {
    return __uint_as_float(((unsigned)s) << 16);
}
__device__ __forceinline__ f32x4 mfma16(bf16x8 a, bf16x8 b, f32x4 c) {
    return __builtin_amdgcn_mfma_f32_16x16x32_bf16(a, b, c, 0, 0, 0);
}
__device__ __forceinline__ void gload16(const unsigned short* g, unsigned short* l) {
    __builtin_amdgcn_global_load_lds(
        (const __attribute__((address_space(1))) void*)g,
        (__attribute__((address_space(3))) void*)l,
        16, 0, 0);
}

// 0.125 (1/sqrt(dk)) * log2(e): folded into qu/qv so softmax runs in exp2 domain
#define QSCALE 0.18033688011112042f

// ---------------------------------------------------------------------------
// split4: batched f32 -> hi/lo bf16 split
// ---------------------------------------------------------------------------
struct SplitA {
    const float* s[4];
    unsigned short* h[4];
    unsigned short* l[4];
    long n[4];
};
__global__ __launch_bounds__(256) void split4(SplitA a)
{
    const int seg = blockIdx.y;
    long i4 = ((long)blockIdx.x * 256 + threadIdx.x) * 4;
    if (i4 >= a.n[seg]) return;
    f32x4 v = *(const f32x4*)(a.s[seg] + i4);
    u16x4 hh, ll;
    #pragma unroll
    for (int i = 0; i < 4; ++i) {
        unsigned short hb = f2bf(v[i]);
        hh[i] = hb;
        ll[i] = f2bf(v[i] - bf2f(hb));
    }
    *(u16x4*)(a.h[seg] + i4) = hh;
    *(u16x4*)(a.l[seg] + i4) = ll;
}

// ---------------------------------------------------------------------------
// prep_wb: batched  w[512][512] f32 -> wh/wl[n][k] bf16 (transpose + split)
// ---------------------------------------------------------------------------
struct PrepW {
    const float* w[5];
    unsigned short* wh[5];
    unsigned short* wl[5];
};
__global__ __launch_bounds__(256) void prep_wb(PrepW p)
{
    const int z = blockIdx.z;
    const float* w = p.w[z];
    unsigned short* wh = p.wh[z];
    unsigned short* wl = p.wl[z];
    __shared__ float sW[32][36];
    const int t = threadIdx.x;
    const int n0 = blockIdx.x * 32, k0 = blockIdx.y * 32;
    {
        int kr = t >> 3, c4 = (t & 7) * 4;
        f32x4 v = *(const f32x4*)(w + (size_t)(k0 + kr) * 512 + n0 + c4);
        #pragma unroll
        for (int i = 0; i < 4; ++i) sW[kr][c4 + i] = v[i];
    }
    __syncthreads();
    {
        int nr = t >> 3, kc = (t & 7) * 4;
        u16x4 hv, lv;
        #pragma unroll
        for (int i = 0; i < 4; ++i) {
            float f = sW[kc + i][nr];
            unsigned short hb = f2bf(f);
            hv[i] = hb;
            lv[i] = f2bf(f - bf2f(hb));
        }
        *(u16x4*)(wh + (size_t)(n0 + nr) * 512 + k0 + kc) = hv;
        *(u16x4*)(wl + (size_t)(n0 + nr) * 512 + k0 + kc) = lv;
    }
}

// ---------------------------------------------------------------------------
// misc_k: blocks 0,1 -> bias_eff = b_ao @ w_o + b_o ; block 2 -> zero pb slack
// ---------------------------------------------------------------------------
__global__ __launch_bounds__(256) void misc_k(
    const float* __restrict__ b_ao, const float* __restrict__ w_o,
    const float* __restrict__ b_o, float* __restrict__ be,
    unsigned short* __restrict__ pb_base)
{
    if (blockIdx.x < 2) {
        int n = blockIdx.x * 256 + threadIdx.x;
        float s = b_o[n];
        for (int j = 0; j < 512; ++j) s += b_ao[j] * w_o[(size_t)j * 512 + n];
        be[n] = s;
    } else {
        ((unsigned int*)pb_base)[threadIdx.x] = 0u;
    }
}

// ---------------------------------------------------------------------------
// gemm_core: round-5 proven 2-phase pipeline (stage-early + __syncthreads).
// Tile = (MF*32) x 128, BK=32, 4 waves, global_load_lds + 4-slot XOR swizzle.
// Split product: Ah*Wh + Ah*Wl + Al*Wh (3 MFMAs) ~= f32 accuracy.
// ---------------------------------------------------------------------------
template<int MF>
__device__ __forceinline__ void gemm_core(
    f32x4 (&acc)[MF][4],
    const unsigned short* __restrict__ Ah_g,
    const unsigned short* __restrict__ Al_g, int lda,
    const unsigned short* __restrict__ Wh_g,
    const unsigned short* __restrict__ Wl_g,
    int M, int row0, int col0,
    unsigned short* sAh, unsigned short* sAl,
    unsigned short* sWh, unsigned short* sWl)
{
    const int t = threadIdx.x;
    const int lane = t & 63, w = t >> 6;
    const int wm = w >> 1, wn = w & 1;
    const int ln15 = lane & 15, g4 = lane >> 4;
    const int ASZ = MF * 32 * 32;
    const int WSZ = 128 * 32;

    auto stage = [&](int kt, int buf) {
        #pragma unroll
        for (int l = 0; l < MF / 2; ++l) {
            int e = l * 256 + w * 64 + lane;
            int row = e >> 2, slot = e & 3;
            int ss = slot ^ (row & 3);
            int gr = row0 + row;
            if (gr > M - 1) gr = M - 1;
            size_t ga = (size_t)gr * lda + kt * 32 + ss * 8;
            gload16(Ah_g + ga, sAh + buf * ASZ + (l * 256 + w * 64) * 8);
            gload16(Al_g + ga, sAl + buf * ASZ + (l * 256 + w * 64) * 8);
        }
        #pragma unroll
        for (int l = 0; l < 2; ++l) {
            int e = l * 256 + w * 64 + lane;
            int row = e >> 2, slot = e & 3;
            int ss = slot ^ (row & 3);
            size_t gw = (size_t)(col0 + row) * 512 + kt * 32 + ss * 8;
            gload16(Wh_g + gw, sWh + buf * WSZ + (l * 256 + w * 64) * 8);
            gload16(Wl_g + gw, sWl + buf * WSZ + (l * 256 + w * 64) * 8);
        }
    };
    auto comp = [&](int buf) {
        bf16x8 fah[MF], fal[MF], fwh[4], fwl[4];
        #pragma unroll
        for (int i = 0; i < MF; ++i) {
            int ar = wm * (MF * 16) + i * 16 + ln15;
            int sa = (g4 ^ (ar & 3)) * 8;
            fah[i] = *(const bf16x8*)&sAh[buf * ASZ + ar * 32 + sa];
            fal[i] = *(const bf16x8*)&sAl[buf * ASZ + ar * 32 + sa];
        }
        #pragma unroll
        for (int j = 0; j < 4; ++j) {
            int wr = wn * 64 + j * 16 + ln15;
            int sw = (g4 ^ (wr & 3)) * 8;
            fwh[j] = *(const bf16x8*)&sWh[buf * WSZ + wr * 32 + sw];
            fwl[j] = *(const bf16x8*)&sWl[buf * WSZ + wr * 32 + sw];
        }
        __builtin_amdgcn_s_setprio(1);
        #pragma unroll
        for (int mi = 0; mi < MF; ++mi)
            #pragma unroll
            for (int ni = 0; ni < 4; ++ni) {
                acc[mi][ni] = mfma16(fah[mi], fwh[ni], acc[mi][ni]);
                acc[mi][ni] = mfma16(fah[mi], fwl[ni], acc[mi][ni]);
                acc[mi][ni] = mfma16(fal[mi], fwh[ni], acc[mi][ni]);
            }
        __builtin_amdgcn_s_setprio(0);
    };

    stage(0, 0);
    __syncthreads();
    for (int k2 = 0; k2 < 8; ++k2) {
        stage(2 * k2 + 1, 1);
        comp(0);
        __syncthreads();
        if (k2 < 7) stage(2 * k2 + 2, 0);
        comp(1);
        __syncthreads();
    }
}

#define GEMM_LDS(MF) \
    __shared__ __align__(16) unsigned short sAh[2][MF * 32 * 32]; \
    __shared__ __align__(16) unsigned short sAl[2][MF * 32 * 32]; \
    __shared__ __align__(16) unsigned short sWh[2][128 * 32];     \
    __shared__ __align__(16) unsigned short sWl[2][128 * 32];

// ---- fused QKV projection GEMM: N = 1536 (q|k|v), routed epilogue ----
__global__ __launch_bounds__(256, 2) void gemm_qkv(
    const unsigned short* __restrict__ Ah_g,
    const unsigned short* __restrict__ Al_g,
    const unsigned short* __restrict__ Wh_g,
    const unsigned short* __restrict__ Wl_g,
    const float* __restrict__ b_q, const float* __restrict__ bu,
    const float* __restrict__ bv, const float* __restrict__ b_k,
    const float* __restrict__ b_v,
    unsigned short* __restrict__ qu, unsigned short* __restrict__ qv,
    unsigned short* __restrict__ kb, unsigned short* __restrict__ vt)
{
    GEMM_LDS(4)
    f32x4 acc[4][4];
    #pragma unroll
    for (int i = 0; i < 4; ++i)
        #pragma unroll
        for (int j = 0; j < 4; ++j) acc[i][j] = (f32x4){0.f, 0.f, 0.f, 0.f};
    const int row0 = blockIdx.y * 128, col0 = blockIdx.x * 128;
    gemm_core<4>(acc, Ah_g, Al_g, 512, Wh_g, Wl_g, BT_, row0, col0,
                 &sAh[0][0], &sAl[0][0], &sWh[0][0], &sWl[0][0]);

    const int t = threadIdx.x;
    const int lane = t & 63, w = t >> 6;
    const int wm = w >> 1, wn = w & 1;
    const int ln15 = lane & 15, g4 = lane >> 4;
    const int grp = col0 >> 9;   // 0=q, 1=k, 2=v (block-uniform)

    if (grp == 2) {
        #pragma unroll
        for (int mi = 0; mi < 4; ++mi) {
            int gr0 = row0 + wm * 64 + mi * 16 + g4 * 4;
            int bb = gr0 >> 10, t0 = gr0 & 1023;
            #pragma unroll
            for (int ni = 0; ni < 4; ++ni) {
                int gcl = (col0 & 511) + wn * 64 + ni * 16 + ln15;
                float bias = b_v[gcl];
                u16x4 vv;
                #pragma unroll
                for (int r4 = 0; r4 < 4; ++r4) vv[r4] = f2bf(acc[mi][ni][r4] + bias);
                *(u16x4*)(vt + ((size_t)(bb * 512 + gcl)) * 1024 + t0) = vv;
            }
        }
    } else {
        #pragma unroll
        for (int mi = 0; mi < 4; ++mi)
            #pragma unroll
            for (int r4 = 0; r4 < 4; ++r4) {
                int gr = row0 + wm * 64 + mi * 16 + g4 * 4 + r4;
                #pragma unroll
                for (int ni = 0; ni < 4; ++ni) {
                    int gcl = (col0 & 511) + wn * 64 + ni * 16 + ln15;
                    float a = acc[mi][ni][r4];
                    if (grp == 0) {
                        // fold 0.125*log2e (exp2-domain softmax) here
                        float base = a + b_q[gcl];
                        qu[(size_t)gr * 512 + gcl] = f2bf((base + bu[gcl]) * QSCALE);
                        qv[(size_t)gr * 512 + gcl] = f2bf((base + bv[gcl]) * QSCALE);
                    } else {
                        kb[(size_t)gr * 512 + gcl] = f2bf(a + b_k[gcl]);
                    }
                }
            }
    }
}

// ---- pos projection GEMM -> bf16 pb ----
__global__ __launch_bounds__(256, 2) void gemm_pos(
    const unsigned short* __restrict__ Ah_g,
    const unsigned short* __restrict__ Al_g,
    const unsigned short* __restrict__ Wh_g,
    const unsigned short* __restrict__ Wl_g,
    unsigned short* __restrict__ pb0)
{
    GEMM_LDS(4)
    f32x4 acc[4][4];
    #pragma unroll
    for (int i = 0; i < 4; ++i)
        #pragma unroll
        for (int j = 0; j < 4; ++j) acc[i][j] = (f32x4){0.f, 0.f, 0.f, 0.f};
    const int row0 = blockIdx.y * 128, col0 = blockIdx.x * 128;
    gemm_core<4>(acc, Ah_g, Al_g, 512, Wh_g, Wl_g, PLEN_, row0, col0,
                 &sAh[0][0], &sAl[0][0], &sWh[0][0], &sWl[0][0]);

    const int t = threadIdx.x;
    const int lane = t & 63, w = t >> 6;
    const int wm = w >> 1, wn = w & 1;
    const int ln15 = lane & 15, g4 = lane >> 4;
    #pragma unroll
    for (int mi = 0; mi < 4; ++mi)
        #pragma unroll
        for (int r4 = 0; r4 < 4; ++r4) {
            int gr = row0 + wm * 64 + mi * 16 + g4 * 4 + r4;
            if (gr >= PLEN_) continue;
            #pragma unroll
            for (int ni = 0; ni < 4; ++ni) {
                int gc = col0 + wn * 64 + ni * 16 + ln15;
                pb0[(size_t)gr * 512 + gc] = f2bf(acc[mi][ni][r4]);
            }
        }
}

// ---- effective-weight GEMMs (batched, f32 out); 64x128 tiles, 128 blocks ----
struct WeffA {
    const unsigned short* ah[4];
    const unsigned short* al[4];
    int lda[4];
    const unsigned short* wh[4];
    const unsigned short* wl[4];
    float* c[4];
};
__global__ __launch_bounds__(256, 3) void gemm_weff(WeffA a)
{
    GEMM_LDS(2)
    const int z = blockIdx.z;
    f32x4 acc[2][4];
    #pragma unroll
    for (int i = 0; i < 2; ++i)
        #pragma unroll
        for (int j = 0; j < 4; ++j) acc[i][j] = (f32x4){0.f, 0.f, 0.f, 0.f};
    const int row0 = blockIdx.y * 64, col0 = blockIdx.x * 128;
    gemm_core<2>(acc, a.ah[z], a.al[z], a.lda[z], a.wh[z], a.wl[z],
                 512, row0, col0, &sAh[0][0], &sAl[0][0], &sWh[0][0], &sWl[0][0]);

    const int t = threadIdx.x;
    const int lane = t & 63, w = t >> 6;
    const int wm = w >> 1, wn = w & 1;
    const int ln15 = lane & 15, g4 = lane >> 4;
    float* C = a.c[z];
    #pragma unroll
    for (int mi = 0; mi < 2; ++mi)
        #pragma unroll
        for (int r4 = 0; r4 < 4; ++r4) {
            int gr = row0 + wm * 32 + mi * 16 + g4 * 4 + r4;
            #pragma unroll
            for (int ni = 0; ni < 4; ++ni) {
                int gc = col0 + wn * 64 + ni * 16 + ln15;
                C[(size_t)gr * 512 + gc] = acc[mi][ni][r4];
            }
        }
}

// ---- output GEMM: 64x128 tiles, f32 out ----
__global__ __launch_bounds__(256, 3) void gemm_out(
    const unsigned short* __restrict__ Ah_g,
    const unsigned short* __restrict__ Al_g,
    const unsigned short* __restrict__ Wh_g,
    const unsigned short* __restrict__ Wl_g,
    const float* __restrict__ beff, float* __restrict__ C)
{
    GEMM_LDS(2)
    f32x4 acc[2][4];
    #pragma unroll
    for (int i = 0; i < 2; ++i)
        #pragma unroll
        for (int j = 0; j < 4; ++j) acc[i][j] = (f32x4){0.f, 0.f, 0.f, 0.f};
    const int row0 = blockIdx.y * 64, col0 = blockIdx.x * 128;
    gemm_core<2>(acc, Ah_g, Al_g, 512, Wh_g, Wl_g, BT_, row0, col0,
                 &sAh[0][0], &sAl[0][0], &sWh[0][0], &sWl[0][0]);

    const int t = threadIdx.x;
    const int lane = t & 63, w = t >> 6;
    const int wm = w >> 1, wn = w & 1;
    const int ln15 = lane & 15, g4 = lane >> 4;
    #pragma unroll
    for (int mi = 0; mi < 2; ++mi)
        #pragma unroll
        for (int r4 = 0; r4 < 4; ++r4) {
            int gr = row0 + wm * 32 + mi * 16 + g4 * 4 + r4;
            #pragma unroll
            for (int ni = 0; ni < 4; ++ni) {
                int gc = col0 + wn * 64 + ni * 16 + ln15;
                C[(size_t)gr * 512 + gc] = acc[mi][ni][r4] + beff[gc];
            }
        }
}

// ---------------------------------------------------------------------------
// attn_v6: round-5 proven attn_v3 skeleton + exp2-domain softmax (QSCALE
// pre-folded into qu/qv), m init -1e30 (no inf arithmetic anywhere; -1e30 is
// integer-valued so even a range-reducing exp2f computes r=0, not NaN).
// f2bf packing, always-rescale (cvtpk/defer-max reverted pending bisect).
// ---------------------------------------------------------------------------
__global__ __launch_bounds__(256, 2) void attn_v6(
    const unsigned short* __restrict__ qu_g,
    const unsigned short* __restrict__ qv_g,
    const unsigned short* __restrict__ kb_g,
    const unsigned short* __restrict__ vt_g,
    const unsigned short* __restrict__ pb_g,   // p=0 (zeroed 512-slack before)
    unsigned short* __restrict__ atth,
    unsigned short* __restrict__ attl)
{
    __shared__ __align__(16) unsigned short sK[2][64 * 64];
    __shared__ __align__(16) unsigned short sP[2][64 * 64];
    __shared__ __align__(16) unsigned short sV[2][64 * 64];   // [d][token]
    __shared__ __align__(16) unsigned short ringb[64][132];   // rotated bf16 ring
    __shared__ __align__(16) unsigned short sProb[64][72];    // [q][k]

    const int t = threadIdx.x;
    const int lane = t & 63, w = t >> 6;
    const int ln15 = lane & 15, g4 = lane >> 4;

    // XCD-aware swizzle (1024 blocks, 8 XCDs, bijective)
    const int wg = blockIdx.x;
    const int idx = (wg & 7) * 128 + (wg >> 3);
    const int q0 = (idx & 15) * 64;
    const int bh = idx >> 4;
    const int h = bh & 7, b = bh >> 3;
    const size_t tok0 = (size_t)b * T_;
    const int hd = h * DK_;
    const int qq = w * 16 + ln15;           // this lane's q row

    auto stage_chunk = [&](int c, int buf) {
        #pragma unroll
        for (int l = 0; l < 2; ++l) {
            int e = l * 256 + w * 64 + lane;
            int row = e >> 3, slot = e & 7;
            int sl = slot ^ (row & 7);
            int lofs = buf * 4096 + (l * 256 + w * 64) * 8;
            gload16(kb_g + (tok0 + c * 64 + row) * INNER_ + hd + sl * 8, &sK[0][lofs]);
            gload16(vt_g + ((size_t)(b * H_ + h) * DK_ + row) * T_ + c * 64 + sl * 8, &sV[0][lofs]);
            long p = (long)(c * 64 - q0 + 1023 + row);
            gload16(pb_g + p * INNER_ + hd + sl * 8, &sP[0][lofs]);
        }
    };

    // ---- stage Qu -> sK[0], Qv -> sP[0]; pull fragments ----
    #pragma unroll
    for (int l = 0; l < 2; ++l) {
        int e = l * 256 + w * 64 + lane;
        int row = e >> 3, slot = e & 7;
        int sl = slot ^ (row & 7);
        size_t src = (tok0 + q0 + row) * INNER_ + hd + sl * 8;
        gload16(qu_g + src, &sK[0][(l * 256 + w * 64) * 8]);
        gload16(qv_g + src, &sP[0][(l * 256 + w * 64) * 8]);
    }
    __syncthreads();
    bf16x8 fqu[2], fqv[2];
    #pragma unroll
    for (int ki = 0; ki < 2; ++ki) {
        int sl = (ki * 4 + g4) ^ (qq & 7);
        fqu[ki] = *(const bf16x8*)&sK[0][qq * 64 + sl * 8];
        fqv[ki] = *(const bf16x8*)&sP[0][qq * 64 + sl * 8];
    }
    __syncthreads();   // all waves hold frags before buffers are overwritten

    // ---- stage prologue-P window -> sP[1] AND chunk0 -> buf0 ----
    #pragma unroll
    for (int l = 0; l < 2; ++l) {
        int e = l * 256 + w * 64 + lane;
        int row = e >> 3, slot = e & 7;
        int sl = slot ^ (row & 7);
        long p = (long)(959 - q0 + row);
        gload16(pb_g + p * INNER_ + hd + sl * 8, &sP[0][4096 + (l * 256 + w * 64) * 8]);
    }
    stage_chunk(0, 0);
    __syncthreads();

    // ---- ring prologue (window rows -> ring pos 0..63, rotated by qq) ----
    #pragma unroll
    for (int n = 0; n < 4; ++n) {
        f32x4 bdv = {0.f, 0.f, 0.f, 0.f};
        #pragma unroll
        for (int ki = 0; ki < 2; ++ki) {
            int prow = n * 16 + ln15;
            int sl = (ki * 4 + g4) ^ (prow & 7);
            bf16x8 pf = *(const bf16x8*)&sP[0][4096 + prow * 64 + sl * 8];
            bdv = mfma16(pf, fqv[ki], bdv);
        }
        #pragma unroll
        for (int r4 = 0; r4 < 4; ++r4)
            ringb[qq][(n * 16 + g4 * 4 + r4 + qq) & 127] = f2bf(bdv[r4]);
    }
    __syncthreads();   // sP[1] free for chunk-1 prefetch

    float m = -1e30f, den = 0.f;
    f32x4 o[4];
    #pragma unroll
    for (int i = 0; i < 4; ++i) o[i] = (f32x4){0.f, 0.f, 0.f, 0.f};

    auto compute_chunk = [&](int c, int buf) {
        const int bofs = buf * 4096;
        f32x4 sc[4], bd[4];
        #pragma unroll
        for (int n = 0; n < 4; ++n) {
            sc[n] = (f32x4){0.f, 0.f, 0.f, 0.f};
            bd[n] = (f32x4){0.f, 0.f, 0.f, 0.f};
        }
        __builtin_amdgcn_s_setprio(1);
        #pragma unroll
        for (int ki = 0; ki < 2; ++ki)
            #pragma unroll
            for (int n = 0; n < 4; ++n) {
                int krow = n * 16 + ln15;
                int sl = (ki * 4 + g4) ^ (krow & 7);
                bf16x8 kf = *(const bf16x8*)&sK[0][bofs + krow * 64 + sl * 8];
                sc[n] = mfma16(kf, fqu[ki], sc[n]);
                bf16x8 pf = *(const bf16x8*)&sP[0][bofs + krow * 64 + sl * 8];
                bd[n] = mfma16(pf, fqv[ki], bd[n]);
            }
        __builtin_amdgcn_s_setprio(0);

        // ring write (rotated; off critical path)
        const int pbase = (c & 1) ? 0 : 64;
        #pragma unroll
        for (int n = 0; n < 4; ++n)
            #pragma unroll
            for (int r4 = 0; r4 < 4; ++r4)
                ringb[qq][(pbase + n * 16 + g4 * 4 + r4 + qq) & 127] = f2bf(bd[n][r4]);

        // scores + online softmax in exp2 domain (scale pre-folded)
        float s[4][4];
        float mx = -1e30f;
        #pragma unroll
        for (int n = 0; n < 4; ++n) {
            const int st2 = (c * 64 + 64 + n * 16 + g4 * 4) & 127;  // 4-aligned
            u16x4 rv = *(const u16x4*)&ringb[qq][st2];
            #pragma unroll
            for (int r4 = 0; r4 < 4; ++r4) {
                float v = sc[n][r4] + bf2f(rv[r4]);
                s[n][r4] = v;
                mx = fmaxf(mx, v);
            }
        }
        mx = fmaxf(mx, __shfl_xor(mx, 16));
        mx = fmaxf(mx, __shfl_xor(mx, 32));
        float newm = fmaxf(m, mx);
        float scale = exp2f(m - newm);   // m,newm finite always (init -1e30)
        m = newm;
        float ls = 0.f;
        #pragma unroll
        for (int n = 0; n < 4; ++n) {
            u16x4 pv4;
            #pragma unroll
            for (int r4 = 0; r4 < 4; ++r4) {
                float p = exp2f(s[n][r4] - newm);
                ls += p;
                pv4[r4] = f2bf(p);
            }
            *(u16x4*)&sProb[qq][n * 16 + g4 * 4] = pv4;
        }
        ls += __shfl_xor(ls, 16);
        ls += __shfl_xor(ls, 32);
        den = den * scale + ls;
        #pragma unroll
        for (int n2 = 0; n2 < 4; ++n2) {
            o[n2][0] *= scale; o[n2][1] *= scale;
            o[n2][2] *= scale; o[n2][3] *= scale;
        }

        // PV: O^T[d,q] += V[d,tok] @ P[tok,q]
        __builtin_amdgcn_s_setprio(1);
        #pragma unroll
        for (int ki = 0; ki < 2; ++ki) {
            bf16x8 pa = *(const bf16x8*)&sProb[qq][ki * 32 + g4 * 8];
            #pragma unroll
            for (int n2 = 0; n2 < 4; ++n2) {
                int drow = n2 * 16 + ln15;
                int sl = (ki * 4 + g4) ^ (drow & 7);
                bf16x8 vf = *(const bf16x8*)&sV[0][bofs + drow * 64 + sl * 8];
                o[n2] = mfma16(vf, pa, o[n2]);
            }
        }
        __builtin_amdgcn_s_setprio(0);
    };

    // ---- main loop (round-5 proven): stage(c+1) -> compute(c) -> barrier ----
    for (int c2 = 0; c2 < 8; ++c2) {
        int c = c2 * 2;
        stage_chunk(c + 1, 1);
        compute_chunk(c, 0);
        __syncthreads();
        if (c2 < 7) stage_chunk(c + 2, 0);
        compute_chunk(c + 1, 1);
        __syncthreads();
    }

    const float inv = 1.0f / den;
    #pragma unroll
    for (int n2 = 0; n2 < 4; ++n2) {
        u16x4 hv, lv;
        #pragma unroll
        for (int r4 = 0; r4 < 4; ++r4) {
            float val = o[n2][r4] * inv;
            unsigned short hb = f2bf(val);
            hv[r4] = hb;
            lv[r4] = f2bf(val - bf2f(hb));
        }
        size_t oidx = (tok0 + q0 + qq) * INNER_ + hd + n2 * 16 + g4 * 4;
        *(u16x4*)(atth + oidx) = hv;
        *(u16x4*)(attl + oidx) = lv;
    }
}

// ---------------------------------------------------------------------------
extern "C" void kernel_launch(void* const* d_in, const int* in_sizes, int n_in,
                              void* d_out, int out_size, void* d_ws, size_t ws_size,
                              hipStream_t stream)
{
    const float* x     = (const float*)d_in[0];
    const float* pos   = (const float*)d_in[1];
    const float* w_qkv = (const float*)d_in[2];
    const float* w_q   = (const float*)d_in[3];
    const float* b_q   = (const float*)d_in[4];
    const float* w_k   = (const float*)d_in[5];
    const float* b_k   = (const float*)d_in[6];
    const float* w_v   = (const float*)d_in[7];
    const float* b_v   = (const float*)d_in[8];
    const float* w_pos = (const float*)d_in[9];
    const float* bu    = (const float*)d_in[10];
    const float* bv    = (const float*)d_in[11];
    const float* w_ao  = (const float*)d_in[12];
    const float* b_ao  = (const float*)d_in[13];
    const float* w_o   = (const float*)d_in[14];
    const float* b_o   = (const float*)d_in[15];
    float* out = (float*)d_out;

    unsigned short* u = (unsigned short*)d_ws;
    const size_t SZ = (size_t)BT_ * INNER_;          // 4,194,304
    unsigned short* xh   = u;
    unsigned short* xl   = xh + SZ;
    unsigned short* qu   = xl + SZ;
    unsigned short* qv   = qu + SZ;
    unsigned short* kb   = qv + SZ;
    unsigned short* vt   = kb + SZ;
    unsigned short* atth = vt + SZ;
    unsigned short* attl = atth + SZ;
    unsigned short* pb_base = attl + SZ;             // 512 slack + 2047*512
    unsigned short* pb0  = pb_base + 512;
    unsigned short* posh = pb_base + 1049600;
    unsigned short* posl = posh + 1049600;
    unsigned short* wqkvh = posl + 1049600;
    unsigned short* wqkvl = wqkvh + 786432;
    unsigned short* waoh  = wqkvl + 786432;
    unsigned short* waol  = waoh + 262144;
    unsigned short* w5    = waol + 262144;   // wq,wk,wv,wo,wp (h,l)
    unsigned short* wq_h = w5;              unsigned short* wq_l = w5 + 262144;
    unsigned short* wk_h = w5 + 2*262144;   unsigned short* wk_l = w5 + 3*262144;
    unsigned short* wv_h = w5 + 4*262144;   unsigned short* wv_l = w5 + 5*262144;
    unsigned short* wo_h = w5 + 6*262144;   unsigned short* wo_l = w5 + 7*262144;
    unsigned short* wp_h = w5 + 8*262144;   unsigned short* wp_l = w5 + 9*262144;
    float* weffC = (float*)(w5 + 10*262144);           // 4 x 262144 f32
    unsigned short* wcat_h = (unsigned short*)(weffC + 4*262144);
    unsigned short* wcat_l = wcat_h + 786432;
    unsigned short* woe_h  = wcat_l + 786432;
    unsigned short* woe_l  = woe_h + 262144;
    float* beff = (float*)(woe_l + 262144);

    dim3 blk(256);

    // 1) input/weight splits (one batched launch)
    SplitA sa;
    sa.s[0] = x;     sa.h[0] = xh;    sa.l[0] = xl;    sa.n[0] = (long)SZ;
    sa.s[1] = w_qkv; sa.h[1] = wqkvh; sa.l[1] = wqkvl; sa.n[1] = 786432L;
    sa.s[2] = w_ao;  sa.h[2] = waoh;  sa.l[2] = waol;  sa.n[2] = 262144L;
    sa.s[3] = pos;   sa.h[3] = posh;  sa.l[3] = posl;  sa.n[3] = (long)PLEN_ * 512;
    split4<<<dim3(4096, 4), blk, 0, stream>>>(sa);

    // 2) transpose+split the five raw 512x512 weights
    PrepW p5;
    p5.w[0] = w_q;   p5.wh[0] = wq_h; p5.wl[0] = wq_l;
    p5.w[1] = w_k;   p5.wh[1] = wk_h; p5.wl[1] = wk_l;
    p5.w[2] = w_v;   p5.wh[2] = wv_h; p5.wl[2] = wv_l;
    p5.w[3] = w_o;   p5.wh[3] = wo_h; p5.wl[3] = wo_l;
    p5.w[4] = w_pos; p5.wh[4] = wp_h; p5.wl[4] = wp_l;
    prep_wb<<<dim3(16, 16, 5), blk, 0, stream>>>(p5);

    // 3) effective weights: Wq/k/v_eff = Wqkv_slice @ W*, Wo_eff = Wao @ Wo
    WeffA wa;
    wa.ah[0] = wqkvh;        wa.al[0] = wqkvl;        wa.lda[0] = 1536;
    wa.ah[1] = wqkvh + 512;  wa.al[1] = wqkvl + 512;  wa.lda[1] = 1536;
    wa.ah[2] = wqkvh + 1024; wa.al[2] = wqkvl + 1024; wa.lda[2] = 1536;
    wa.ah[3] = waoh;         wa.al[3] = waol;         wa.lda[3] = 512;
    wa.wh[0] = wq_h; wa.wl[0] = wq_l;
    wa.wh[1] = wk_h; wa.wl[1] = wk_l;
    wa.wh[2] = wv_h; wa.wl[2] = wv_l;
    wa.wh[3] = wo_h; wa.wl[3] = wo_l;
    wa.c[0] = weffC;             wa.c[1] = weffC + 262144;
    wa.c[2] = weffC + 2*262144;  wa.c[3] = weffC + 3*262144;
    gemm_weff<<<dim3(4, 8, 4), blk, 0, stream>>>(wa);

    // 4) transpose+split effective weights (q|k|v concat + wo_eff)
    PrepW p4;
    p4.w[0] = weffC;            p4.wh[0] = wcat_h;            p4.wl[0] = wcat_l;
    p4.w[1] = weffC + 262144;   p4.wh[1] = wcat_h + 262144;   p4.wl[1] = wcat_l + 262144;
    p4.w[2] = weffC + 2*262144; p4.wh[2] = wcat_h + 2*262144; p4.wl[2] = wcat_l + 2*262144;
    p4.w[3] = weffC + 3*262144; p4.wh[3] = woe_h;             p4.wl[3] = woe_l;
    p4.w[4] = nullptr; p4.wh[4] = nullptr; p4.wl[4] = nullptr;
    prep_wb<<<dim3(16, 16, 4), blk, 0, stream>>>(p4);

    // 5) bias_eff + pb slack zero
    misc_k<<<3, blk, 0, stream>>>(b_ao, w_o, b_o, beff, pb_base);

    // 6) fused q/k/v projection + pos projection
    gemm_qkv<<<dim3(12, 64), blk, 0, stream>>>(xh, xl, wcat_h, wcat_l,
        b_q, bu, bv, b_k, b_v, qu, qv, kb, vt);
    gemm_pos<<<dim3(4, 16), blk, 0, stream>>>(posh, posl, wp_h, wp_l, pb0);

    // 7) attention
    attn_v6<<<1024, blk, 0, stream>>>(qu, qv, kb, vt, pb0, atth, attl);

    // 8) output GEMM
    gemm_out<<<dim3(4, 128), blk, 0, stream>>>(atth, attl, woe_h, woe_l, beff, out);
}

// Round 10
// 193.061 us; speedup vs baseline: 9.5734x; 1.1817x over previous
//
#include <hip/hip_runtime.h>
#include <hip/hip_bf16.h>
#include <math.h>

#define H_     8
#define DK_    64
#define INNER_ 512
#define B_     8
#define T_     1024
#define D_     512
#define PLEN_  2047
#define BT_    8192

typedef __attribute__((ext_vector_type(8))) short bf16x8;
typedef __attribute__((ext_vector_type(4))) float f32x4;
typedef __attribute__((ext_vector_type(4))) unsigned short u16x4;
typedef __attribute__((ext_vector_type(8))) unsigned short u16x8;

__device__ __forceinline__ unsigned short f2bf(float f) {
    unsigned u = __float_as_uint(f);
    u += 0x7fffu + ((u >> 16) & 1u);
    return (unsigned short)(u >> 16);
}
__device__ __forceinline__ float bf2f(unsigned short s) {
    return __uint_as_float(((unsigned)s) << 16);
}
__device__ __forceinline__ f32x4 mfma16(bf16x8 a, bf16x8 b, f32x4 c) {
    return __builtin_amdgcn_mfma_f32_16x16x32_bf16(a, b, c, 0, 0, 0);
}
__device__ __forceinline__ void gload16(const unsigned short* g, unsigned short* l) {
    __builtin_amdgcn_global_load_lds(
        (const __attribute__((address_space(1))) void*)g,
        (__attribute__((address_space(3))) void*)l,
        16, 0, 0);
}

// 1/sqrt(dk) folded into qu/qv at the projection epilogue (round-5 proven)
#define QSCALE 0.125f

// ---------------------------------------------------------------------------
// split4: batched f32 -> hi/lo bf16 split
// ---------------------------------------------------------------------------
struct SplitA {
    const float* s[4];
    unsigned short* h[4];
    unsigned short* l[4];
    long n[4];
};
__global__ __launch_bounds__(256) void split4(SplitA a)
{
    const int seg = blockIdx.y;
    long i4 = ((long)blockIdx.x * 256 + threadIdx.x) * 4;
    if (i4 >= a.n[seg]) return;
    f32x4 v = *(const f32x4*)(a.s[seg] + i4);
    u16x4 hh, ll;
    #pragma unroll
    for (int i = 0; i < 4; ++i) {
        unsigned short hb = f2bf(v[i]);
        hh[i] = hb;
        ll[i] = f2bf(v[i] - bf2f(hb));
    }
    *(u16x4*)(a.h[seg] + i4) = hh;
    *(u16x4*)(a.l[seg] + i4) = ll;
}

// ---------------------------------------------------------------------------
// prep_wb: batched  w[512][512] f32 -> wh/wl[n][k] bf16 (transpose + split)
// ---------------------------------------------------------------------------
struct PrepW {
    const float* w[5];
    unsigned short* wh[5];
    unsigned short* wl[5];
};
__global__ __launch_bounds__(256) void prep_wb(PrepW p)
{
    const int z = blockIdx.z;
    const float* w = p.w[z];
    unsigned short* wh = p.wh[z];
    unsigned short* wl = p.wl[z];
    __shared__ float sW[32][36];
    const int t = threadIdx.x;
    const int n0 = blockIdx.x * 32, k0 = blockIdx.y * 32;
    {
        int kr = t >> 3, c4 = (t & 7) * 4;
        f32x4 v = *(const f32x4*)(w + (size_t)(k0 + kr) * 512 + n0 + c4);
        #pragma unroll
        for (int i = 0; i < 4; ++i) sW[kr][c4 + i] = v[i];
    }
    __syncthreads();
    {
        int nr = t >> 3, kc = (t & 7) * 4;
        u16x4 hv, lv;
        #pragma unroll
        for (int i = 0; i < 4; ++i) {
            float f = sW[kc + i][nr];
            unsigned short hb = f2bf(f);
            hv[i] = hb;
            lv[i] = f2bf(f - bf2f(hb));
        }
        *(u16x4*)(wh + (size_t)(n0 + nr) * 512 + k0 + kc) = hv;
        *(u16x4*)(wl + (size_t)(n0 + nr) * 512 + k0 + kc) = lv;
    }
}

// ---------------------------------------------------------------------------
// misc_k: blocks 0,1 -> bias_eff = b_ao @ w_o + b_o ; block 2 -> zero pb slack
// ---------------------------------------------------------------------------
__global__ __launch_bounds__(256) void misc_k(
    const float* __restrict__ b_ao, const float* __restrict__ w_o,
    const float* __restrict__ b_o, float* __restrict__ be,
    unsigned short* __restrict__ pb_base)
{
    if (blockIdx.x < 2) {
        int n = blockIdx.x * 256 + threadIdx.x;
        float s = b_o[n];
        for (int j = 0; j < 512; ++j) s += b_ao[j] * w_o[(size_t)j * 512 + n];
        be[n] = s;
    } else {
        ((unsigned int*)pb_base)[threadIdx.x] = 0u;
    }
}

// ---------------------------------------------------------------------------
// gemm_core: round-8 proven 2-phase pipeline (stage-early + __syncthreads).
// Tile = (MF*32) x 128, BK=32, 4 waves, global_load_lds + 4-slot XOR swizzle.
// ALO=true : 3-MFMA split (Ah*Wh + Ah*Wl + Al*Wh) ~= f32 accuracy.
// ALO=false: 2-MFMA split (Ah*Wh + Ah*Wl) — A at bf16 precision; used only
//            where the OUTPUT is rounded to single bf16 anyway (q/k/v/pos).
// ---------------------------------------------------------------------------
template<int MF, bool ALO>
__device__ __forceinline__ void gemm_core(
    f32x4 (&acc)[MF][4],
    const unsigned short* __restrict__ Ah_g,
    const unsigned short* __restrict__ Al_g, int lda,
    const unsigned short* __restrict__ Wh_g,
    const unsigned short* __restrict__ Wl_g,
    int M, int row0, int col0,
    unsigned short* sAh, unsigned short* sAl,
    unsigned short* sWh, unsigned short* sWl)
{
    const int t = threadIdx.x;
    const int lane = t & 63, w = t >> 6;
    const int wm = w >> 1, wn = w & 1;
    const int ln15 = lane & 15, g4 = lane >> 4;
    const int ASZ = MF * 32 * 32;
    const int WSZ = 128 * 32;

    auto stage = [&](int kt, int buf) {
        #pragma unroll
        for (int l = 0; l < MF / 2; ++l) {
            int e = l * 256 + w * 64 + lane;
            int row = e >> 2, slot = e & 3;
            int ss = slot ^ (row & 3);
            int gr = row0 + row;
            if (gr > M - 1) gr = M - 1;
            size_t ga = (size_t)gr * lda + kt * 32 + ss * 8;
            gload16(Ah_g + ga, sAh + buf * ASZ + (l * 256 + w * 64) * 8);
            if constexpr (ALO)
                gload16(Al_g + ga, sAl + buf * ASZ + (l * 256 + w * 64) * 8);
        }
        #pragma unroll
        for (int l = 0; l < 2; ++l) {
            int e = l * 256 + w * 64 + lane;
            int row = e >> 2, slot = e & 3;
            int ss = slot ^ (row & 3);
            size_t gw = (size_t)(col0 + row) * 512 + kt * 32 + ss * 8;
            gload16(Wh_g + gw, sWh + buf * WSZ + (l * 256 + w * 64) * 8);
            gload16(Wl_g + gw, sWl + buf * WSZ + (l * 256 + w * 64) * 8);
        }
    };
    auto comp = [&](int buf) {
        bf16x8 fah[MF], fal[MF], fwh[4], fwl[4];
        #pragma unroll
        for (int i = 0; i < MF; ++i) {
            int ar = wm * (MF * 16) + i * 16 + ln15;
            int sa = (g4 ^ (ar & 3)) * 8;
            fah[i] = *(const bf16x8*)&sAh[buf * ASZ + ar * 32 + sa];
            if constexpr (ALO)
                fal[i] = *(const bf16x8*)&sAl[buf * ASZ + ar * 32 + sa];
        }
        #pragma unroll
        for (int j = 0; j < 4; ++j) {
            int wr = wn * 64 + j * 16 + ln15;
            int sw = (g4 ^ (wr & 3)) * 8;
            fwh[j] = *(const bf16x8*)&sWh[buf * WSZ + wr * 32 + sw];
            fwl[j] = *(const bf16x8*)&sWl[buf * WSZ + wr * 32 + sw];
        }
        __builtin_amdgcn_s_setprio(1);
        #pragma unroll
        for (int mi = 0; mi < MF; ++mi)
            #pragma unroll
            for (int ni = 0; ni < 4; ++ni) {
                acc[mi][ni] = mfma16(fah[mi], fwh[ni], acc[mi][ni]);
                acc[mi][ni] = mfma16(fah[mi], fwl[ni], acc[mi][ni]);
                if constexpr (ALO)
                    acc[mi][ni] = mfma16(fal[mi], fwh[ni], acc[mi][ni]);
            }
        __builtin_amdgcn_s_setprio(0);
    };

    stage(0, 0);
    __syncthreads();
    for (int k2 = 0; k2 < 8; ++k2) {
        stage(2 * k2 + 1, 1);
        comp(0);
        __syncthreads();
        if (k2 < 7) stage(2 * k2 + 2, 0);
        comp(1);
        __syncthreads();
    }
}

#define GEMM_LDS3(MF) \
    __shared__ __align__(16) unsigned short sAh[2][MF * 32 * 32]; \
    __shared__ __align__(16) unsigned short sAl[2][MF * 32 * 32]; \
    __shared__ __align__(16) unsigned short sWh[2][128 * 32];     \
    __shared__ __align__(16) unsigned short sWl[2][128 * 32];
#define GEMM_LDS2(MF) \
    __shared__ __align__(16) unsigned short sAh[2][MF * 32 * 32]; \
    __shared__ __align__(16) unsigned short sWh[2][128 * 32];     \
    __shared__ __align__(16) unsigned short sWl[2][128 * 32];

// ---- fused QKV projection GEMM: N = 1536 (q|k|v), 2-term split, 48KB LDS ----
__global__ __launch_bounds__(256, 3) void gemm_qkv(
    const unsigned short* __restrict__ Ah_g,
    const unsigned short* __restrict__ Wh_g,
    const unsigned short* __restrict__ Wl_g,
    const float* __restrict__ b_q, const float* __restrict__ bu,
    const float* __restrict__ bv, const float* __restrict__ b_k,
    const float* __restrict__ b_v,
    unsigned short* __restrict__ qu, unsigned short* __restrict__ qv,
    unsigned short* __restrict__ kb, unsigned short* __restrict__ vt)
{
    GEMM_LDS2(4)
    f32x4 acc[4][4];
    #pragma unroll
    for (int i = 0; i < 4; ++i)
        #pragma unroll
        for (int j = 0; j < 4; ++j) acc[i][j] = (f32x4){0.f, 0.f, 0.f, 0.f};
    const int row0 = blockIdx.y * 128, col0 = blockIdx.x * 128;
    gemm_core<4, false>(acc, Ah_g, nullptr, 512, Wh_g, Wl_g, BT_, row0, col0,
                        &sAh[0][0], &sAh[0][0], &sWh[0][0], &sWl[0][0]);

    const int t = threadIdx.x;
    const int lane = t & 63, w = t >> 6;
    const int wm = w >> 1, wn = w & 1;
    const int ln15 = lane & 15, g4 = lane >> 4;
    const int grp = col0 >> 9;   // 0=q, 1=k, 2=v (block-uniform)

    if (grp == 2) {
        #pragma unroll
        for (int mi = 0; mi < 4; ++mi) {
            int gr0 = row0 + wm * 64 + mi * 16 + g4 * 4;
            int bb = gr0 >> 10, t0 = gr0 & 1023;
            #pragma unroll
            for (int ni = 0; ni < 4; ++ni) {
                int gcl = (col0 & 511) + wn * 64 + ni * 16 + ln15;
                float bias = b_v[gcl];
                u16x4 vv;
                #pragma unroll
                for (int r4 = 0; r4 < 4; ++r4) vv[r4] = f2bf(acc[mi][ni][r4] + bias);
                *(u16x4*)(vt + ((size_t)(bb * 512 + gcl)) * 1024 + t0) = vv;
            }
        }
    } else {
        #pragma unroll
        for (int mi = 0; mi < 4; ++mi)
            #pragma unroll
            for (int r4 = 0; r4 < 4; ++r4) {
                int gr = row0 + wm * 64 + mi * 16 + g4 * 4 + r4;
                #pragma unroll
                for (int ni = 0; ni < 4; ++ni) {
                    int gcl = (col0 & 511) + wn * 64 + ni * 16 + ln15;
                    float a = acc[mi][ni][r4];
                    if (grp == 0) {
                        // fold 1/sqrt(dk)=0.125 here (exact pow2 scale)
                        float base = a + b_q[gcl];
                        qu[(size_t)gr * 512 + gcl] = f2bf((base + bu[gcl]) * QSCALE);
                        qv[(size_t)gr * 512 + gcl] = f2bf((base + bv[gcl]) * QSCALE);
                    } else {
                        kb[(size_t)gr * 512 + gcl] = f2bf(a + b_k[gcl]);
                    }
                }
            }
    }
}

// ---- pos projection GEMM -> bf16 pb; 2-term split, 48KB LDS ----
__global__ __launch_bounds__(256, 3) void gemm_pos(
    const unsigned short* __restrict__ Ah_g,
    const unsigned short* __restrict__ Wh_g,
    const unsigned short* __restrict__ Wl_g,
    unsigned short* __restrict__ pb0)
{
    GEMM_LDS2(4)
    f32x4 acc[4][4];
    #pragma unroll
    for (int i = 0; i < 4; ++i)
        #pragma unroll
        for (int j = 0; j < 4; ++j) acc[i][j] = (f32x4){0.f, 0.f, 0.f, 0.f};
    const int row0 = blockIdx.y * 128, col0 = blockIdx.x * 128;
    gemm_core<4, false>(acc, Ah_g, nullptr, 512, Wh_g, Wl_g, PLEN_, row0, col0,
                        &sAh[0][0], &sAh[0][0], &sWh[0][0], &sWl[0][0]);

    const int t = threadIdx.x;
    const int lane = t & 63, w = t >> 6;
    const int wm = w >> 1, wn = w & 1;
    const int ln15 = lane & 15, g4 = lane >> 4;
    #pragma unroll
    for (int mi = 0; mi < 4; ++mi)
        #pragma unroll
        for (int r4 = 0; r4 < 4; ++r4) {
            int gr = row0 + wm * 64 + mi * 16 + g4 * 4 + r4;
            if (gr >= PLEN_) continue;
            #pragma unroll
            for (int ni = 0; ni < 4; ++ni) {
                int gc = col0 + wn * 64 + ni * 16 + ln15;
                pb0[(size_t)gr * 512 + gc] = f2bf(acc[mi][ni][r4]);
            }
        }
}

// ---- effective-weight GEMMs (batched, f32 out); 64x128 tiles, 3-term ----
struct WeffA {
    const unsigned short* ah[4];
    const unsigned short* al[4];
    int lda[4];
    const unsigned short* wh[4];
    const unsigned short* wl[4];
    float* c[4];
};
__global__ __launch_bounds__(256, 3) void gemm_weff(WeffA a)
{
    GEMM_LDS3(2)
    const int z = blockIdx.z;
    f32x4 acc[2][4];
    #pragma unroll
    for (int i = 0; i < 2; ++i)
        #pragma unroll
        for (int j = 0; j < 4; ++j) acc[i][j] = (f32x4){0.f, 0.f, 0.f, 0.f};
    const int row0 = blockIdx.y * 64, col0 = blockIdx.x * 128;
    gemm_core<2, true>(acc, a.ah[z], a.al[z], a.lda[z], a.wh[z], a.wl[z],
                       512, row0, col0,
                       &sAh[0][0], &sAl[0][0], &sWh[0][0], &sWl[0][0]);

    const int t = threadIdx.x;
    const int lane = t & 63, w = t >> 6;
    const int wm = w >> 1, wn = w & 1;
    const int ln15 = lane & 15, g4 = lane >> 4;
    float* C = a.c[z];
    #pragma unroll
    for (int mi = 0; mi < 2; ++mi)
        #pragma unroll
        for (int r4 = 0; r4 < 4; ++r4) {
            int gr = row0 + wm * 32 + mi * 16 + g4 * 4 + r4;
            #pragma unroll
            for (int ni = 0; ni < 4; ++ni) {
                int gc = col0 + wn * 64 + ni * 16 + ln15;
                C[(size_t)gr * 512 + gc] = acc[mi][ni][r4];
            }
        }
}

// ---- output GEMM: 64x128 tiles, f32 out, 3-term ----
__global__ __launch_bounds__(256, 3) void gemm_out(
    const unsigned short* __restrict__ Ah_g,
    const unsigned short* __restrict__ Al_g,
    const unsigned short* __restrict__ Wh_g,
    const unsigned short* __restrict__ Wl_g,
    const float* __restrict__ beff, float* __restrict__ C)
{
    GEMM_LDS3(2)
    f32x4 acc[2][4];
    #pragma unroll
    for (int i = 0; i < 2; ++i)
        #pragma unroll
        for (int j = 0; j < 4; ++j) acc[i][j] = (f32x4){0.f, 0.f, 0.f, 0.f};
    const int row0 = blockIdx.y * 64, col0 = blockIdx.x * 128;
    gemm_core<2, true>(acc, Ah_g, Al_g, 512, Wh_g, Wl_g, BT_, row0, col0,
                       &sAh[0][0], &sAl[0][0], &sWh[0][0], &sWl[0][0]);

    const int t = threadIdx.x;
    const int lane = t & 63, w = t >> 6;
    const int wm = w >> 1, wn = w & 1;
    const int ln15 = lane & 15, g4 = lane >> 4;
    #pragma unroll
    for (int mi = 0; mi < 2; ++mi)
        #pragma unroll
        for (int r4 = 0; r4 < 4; ++r4) {
            int gr = row0 + wm * 32 + mi * 16 + g4 * 4 + r4;
            #pragma unroll
            for (int ni = 0; ni < 4; ++ni) {
                int gc = col0 + wn * 64 + ni * 16 + ln15;
                C[(size_t)gr * 512 + gc] = acc[mi][ni][r4] + beff[gc];
            }
        }
}

// ---------------------------------------------------------------------------
// attn_v8: round-8 proven skeleton (stage-early + __syncthreads dbuf),
// __expf softmax (round-5 proven), 1/8 scale folded into qu/qv, m init -1e30,
// f2bf packing, always-rescale. Lane owns one q row (qq = w*16+ln15);
// BD ring rotated by qq (reads 4-aligned u16x4).
// ---------------------------------------------------------------------------
__global__ __launch_bounds__(256, 2) void attn_v8(
    const unsigned short* __restrict__ qu_g,
    const unsigned short* __restrict__ qv_g,
    const unsigned short* __restrict__ kb_g,
    const unsigned short* __restrict__ vt_g,
    const unsigned short* __restrict__ pb_g,   // p=0 (zeroed 512-slack before)
    unsigned short* __restrict__ atth,
    unsigned short* __restrict__ attl)
{
    __shared__ __align__(16) unsigned short sK[2][64 * 64];
    __shared__ __align__(16) unsigned short sP[2][64 * 64];
    __shared__ __align__(16) unsigned short sV[2][64 * 64];   // [d][token]
    __shared__ __align__(16) unsigned short ringb[64][132];   // rotated bf16 ring
    __shared__ __align__(16) unsigned short sProb[64][72];    // [q][k]

    const int t = threadIdx.x;
    const int lane = t & 63, w = t >> 6;
    const int ln15 = lane & 15, g4 = lane >> 4;

    // XCD-aware swizzle (1024 blocks, 8 XCDs, bijective)
    const int wg = blockIdx.x;
    const int idx = (wg & 7) * 128 + (wg >> 3);
    const int q0 = (idx & 15) * 64;
    const int bh = idx >> 4;
    const int h = bh & 7, b = bh >> 3;
    const size_t tok0 = (size_t)b * T_;
    const int hd = h * DK_;
    const int qq = w * 16 + ln15;           // this lane's q row

    auto stage_chunk = [&](int c, int buf) {
        #pragma unroll
        for (int l = 0; l < 2; ++l) {
            int e = l * 256 + w * 64 + lane;
            int row = e >> 3, slot = e & 7;
            int sl = slot ^ (row & 7);
            int lofs = buf * 4096 + (l * 256 + w * 64) * 8;
            gload16(kb_g + (tok0 + c * 64 + row) * INNER_ + hd + sl * 8, &sK[0][lofs]);
            gload16(vt_g + ((size_t)(b * H_ + h) * DK_ + row) * T_ + c * 64 + sl * 8, &sV[0][lofs]);
            long p = (long)(c * 64 - q0 + 1023 + row);
            gload16(pb_g + p * INNER_ + hd + sl * 8, &sP[0][lofs]);
        }
    };

    // ---- stage Qu -> sK[0], Qv -> sP[0]; pull fragments ----
    #pragma unroll
    for (int l = 0; l < 2; ++l) {
        int e = l * 256 + w * 64 + lane;
        int row = e >> 3, slot = e & 7;
        int sl = slot ^ (row & 7);
        size_t src = (tok0 + q0 + row) * INNER_ + hd + sl * 8;
        gload16(qu_g + src, &sK[0][(l * 256 + w * 64) * 8]);
        gload16(qv_g + src, &sP[0][(l * 256 + w * 64) * 8]);
    }
    __syncthreads();
    bf16x8 fqu[2], fqv[2];
    #pragma unroll
    for (int ki = 0; ki < 2; ++ki) {
        int sl = (ki * 4 + g4) ^ (qq & 7);
        fqu[ki] = *(const bf16x8*)&sK[0][qq * 64 + sl * 8];
        fqv[ki] = *(const bf16x8*)&sP[0][qq * 64 + sl * 8];
    }
    __syncthreads();   // all waves hold frags before buffers are overwritten

    // ---- stage prologue-P window -> sP[1] AND chunk0 -> buf0 ----
    #pragma unroll
    for (int l = 0; l < 2; ++l) {
        int e = l * 256 + w * 64 + lane;
        int row = e >> 3, slot = e & 7;
        int sl = slot ^ (row & 7);
        long p = (long)(959 - q0 + row);
        gload16(pb_g + p * INNER_ + hd + sl * 8, &sP[0][4096 + (l * 256 + w * 64) * 8]);
    }
    stage_chunk(0, 0);
    __syncthreads();

    // ---- ring prologue (window rows -> ring pos 0..63, rotated by qq) ----
    #pragma unroll
    for (int n = 0; n < 4; ++n) {
        f32x4 bdv = {0.f, 0.f, 0.f, 0.f};
        #pragma unroll
        for (int ki = 0; ki < 2; ++ki) {
            int prow = n * 16 + ln15;
            int sl = (ki * 4 + g4) ^ (prow & 7);
            bf16x8 pf = *(const bf16x8*)&sP[0][4096 + prow * 64 + sl * 8];
            bdv = mfma16(pf, fqv[ki], bdv);
        }
        #pragma unroll
        for (int r4 = 0; r4 < 4; ++r4)
            ringb[qq][(n * 16 + g4 * 4 + r4 + qq) & 127] = f2bf(bdv[r4]);
    }
    __syncthreads();   // sP[1] free for chunk-1 prefetch

    float m = -1e30f, den = 0.f;
    f32x4 o[4];
    #pragma unroll
    for (int i = 0; i < 4; ++i) o[i] = (f32x4){0.f, 0.f, 0.f, 0.f};

    auto compute_chunk = [&](int c, int buf) {
        const int bofs = buf * 4096;
        f32x4 sc[4], bd[4];
        #pragma unroll
        for (int n = 0; n < 4; ++n) {
            sc[n] = (f32x4){0.f, 0.f, 0.f, 0.f};
            bd[n] = (f32x4){0.f, 0.f, 0.f, 0.f};
        }
        __builtin_amdgcn_s_setprio(1);
        #pragma unroll
        for (int ki = 0; ki < 2; ++ki)
            #pragma unroll
            for (int n = 0; n < 4; ++n) {
                int krow = n * 16 + ln15;
                int sl = (ki * 4 + g4) ^ (krow & 7);
                bf16x8 kf = *(const bf16x8*)&sK[0][bofs + krow * 64 + sl * 8];
                sc[n] = mfma16(kf, fqu[ki], sc[n]);
                bf16x8 pf = *(const bf16x8*)&sP[0][bofs + krow * 64 + sl * 8];
                bd[n] = mfma16(pf, fqv[ki], bd[n]);
            }
        __builtin_amdgcn_s_setprio(0);

        // ring write (rotated; off critical path)
        const int pbase = (c & 1) ? 0 : 64;
        #pragma unroll
        for (int n = 0; n < 4; ++n)
            #pragma unroll
            for (int r4 = 0; r4 < 4; ++r4)
                ringb[qq][(pbase + n * 16 + g4 * 4 + r4 + qq) & 127] = f2bf(bd[n][r4]);

        // scores + online softmax (1/8 scale pre-folded into qu/qv)
        float s[4][4];
        float mx = -1e30f;
        #pragma unroll
        for (int n = 0; n < 4; ++n) {
            const int st2 = (c * 64 + 64 + n * 16 + g4 * 4) & 127;  // 4-aligned
            u16x4 rv = *(const u16x4*)&ringb[qq][st2];
            #pragma unroll
            for (int r4 = 0; r4 < 4; ++r4) {
                float v = sc[n][r4] + bf2f(rv[r4]);
                s[n][r4] = v;
                mx = fmaxf(mx, v);
            }
        }
        mx = fmaxf(mx, __shfl_xor(mx, 16));
        mx = fmaxf(mx, __shfl_xor(mx, 32));
        float newm = fmaxf(m, mx);
        float scale = __expf(m - newm);   // finite args always (m init -1e30)
        m = newm;
        float ls = 0.f;
        #pragma unroll
        for (int n = 0; n < 4; ++n) {
            u16x4 pv4;
            #pragma unroll
            for (int r4 = 0; r4 < 4; ++r4) {
                float p = __expf(s[n][r4] - newm);
                ls += p;
                pv4[r4] = f2bf(p);
            }
            *(u16x4*)&sProb[qq][n * 16 + g4 * 4] = pv4;
        }
        ls += __shfl_xor(ls, 16);
        ls += __shfl_xor(ls, 32);
        den = den * scale + ls;
        #pragma unroll
        for (int n2 = 0; n2 < 4; ++n2) {
            o[n2][0] *= scale; o[n2][1] *= scale;
            o[n2][2] *= scale; o[n2][3] *= scale;
        }

        // PV: O^T[d,q] += V[d,tok] @ P[tok,q]
        __builtin_amdgcn_s_setprio(1);
        #pragma unroll
        for (int ki = 0; ki < 2; ++ki) {
            bf16x8 pa = *(const bf16x8*)&sProb[qq][ki * 32 + g4 * 8];
            #pragma unroll
            for (int n2 = 0; n2 < 4; ++n2) {
                int drow = n2 * 16 + ln15;
                int sl = (ki * 4 + g4) ^ (drow & 7);
                bf16x8 vf = *(const bf16x8*)&sV[0][bofs + drow * 64 + sl * 8];
                o[n2] = mfma16(vf, pa, o[n2]);
            }
        }
        __builtin_amdgcn_s_setprio(0);
    };

    // ---- main loop (round-8 proven): stage(c+1) -> compute(c) -> barrier ----
    for (int c2 = 0; c2 < 8; ++c2) {
        int c = c2 * 2;
        stage_chunk(c + 1, 1);
        compute_chunk(c, 0);
        __syncthreads();
        if (c2 < 7) stage_chunk(c + 2, 0);
        compute_chunk(c + 1, 1);
        __syncthreads();
    }

    const float inv = 1.0f / den;
    #pragma unroll
    for (int n2 = 0; n2 < 4; ++n2) {
        u16x4 hv, lv;
        #pragma unroll
        for (int r4 = 0; r4 < 4; ++r4) {
            float val = o[n2][r4] * inv;
            unsigned short hb = f2bf(val);
            hv[r4] = hb;
            lv[r4] = f2bf(val - bf2f(hb));
        }
        size_t oidx = (tok0 + q0 + qq) * INNER_ + hd + n2 * 16 + g4 * 4;
        *(u16x4*)(atth + oidx) = hv;
        *(u16x4*)(attl + oidx) = lv;
    }
}

// ---------------------------------------------------------------------------
extern "C" void kernel_launch(void* const* d_in, const int* in_sizes, int n_in,
                              void* d_out, int out_size, void* d_ws, size_t ws_size,
                              hipStream_t stream)
{
    const float* x     = (const float*)d_in[0];
    const float* pos   = (const float*)d_in[1];
    const float* w_qkv = (const float*)d_in[2];
    const float* w_q   = (const float*)d_in[3];
    const float* b_q   = (const float*)d_in[4];
    const float* w_k   = (const float*)d_in[5];
    const float* b_k   = (const float*)d_in[6];
    const float* w_v   = (const float*)d_in[7];
    const float* b_v   = (const float*)d_in[8];
    const float* w_pos = (const float*)d_in[9];
    const float* bu    = (const float*)d_in[10];
    const float* bv    = (const float*)d_in[11];
    const float* w_ao  = (const float*)d_in[12];
    const float* b_ao  = (const float*)d_in[13];
    const float* w_o   = (const float*)d_in[14];
    const float* b_o   = (const float*)d_in[15];
    float* out = (float*)d_out;

    unsigned short* u = (unsigned short*)d_ws;
    const size_t SZ = (size_t)BT_ * INNER_;          // 4,194,304
    unsigned short* xh   = u;
    unsigned short* xl   = xh + SZ;
    unsigned short* qu   = xl + SZ;
    unsigned short* qv   = qu + SZ;
    unsigned short* kb   = qv + SZ;
    unsigned short* vt   = kb + SZ;
    unsigned short* atth = vt + SZ;
    unsigned short* attl = atth + SZ;
    unsigned short* pb_base = attl + SZ;             // 512 slack + 2047*512
    unsigned short* pb0  = pb_base + 512;
    unsigned short* posh = pb_base + 1049600;
    unsigned short* posl = posh + 1049600;
    unsigned short* wqkvh = posl + 1049600;
    unsigned short* wqkvl = wqkvh + 786432;
    unsigned short* waoh  = wqkvl + 786432;
    unsigned short* waol  = waoh + 262144;
    unsigned short* w5    = waol + 262144;   // wq,wk,wv,wo,wp (h,l)
    unsigned short* wq_h = w5;              unsigned short* wq_l = w5 + 262144;
    unsigned short* wk_h = w5 + 2*262144;   unsigned short* wk_l = w5 + 3*262144;
    unsigned short* wv_h = w5 + 4*262144;   unsigned short* wv_l = w5 + 5*262144;
    unsigned short* wo_h = w5 + 6*262144;   unsigned short* wo_l = w5 + 7*262144;
    unsigned short* wp_h = w5 + 8*262144;   unsigned short* wp_l = w5 + 9*262144;
    float* weffC = (float*)(w5 + 10*262144);           // 4 x 262144 f32
    unsigned short* wcat_h = (unsigned short*)(weffC + 4*262144);
    unsigned short* wcat_l = wcat_h + 786432;
    unsigned short* woe_h  = wcat_l + 786432;
    unsigned short* woe_l  = woe_h + 262144;
    float* beff = (float*)(woe_l + 262144);

    dim3 blk(256);

    // 1) input/weight splits (one batched launch)
    SplitA sa;
    sa.s[0] = x;     sa.h[0] = xh;    sa.l[0] = xl;    sa.n[0] = (long)SZ;
    sa.s[1] = w_qkv; sa.h[1] = wqkvh; sa.l[1] = wqkvl; sa.n[1] = 786432L;
    sa.s[2] = w_ao;  sa.h[2] = waoh;  sa.l[2] = waol;  sa.n[2] = 262144L;
    sa.s[3] = pos;   sa.h[3] = posh;  sa.l[3] = posl;  sa.n[3] = (long)PLEN_ * 512;
    split4<<<dim3(4096, 4), blk, 0, stream>>>(sa);

    // 2) transpose+split the five raw 512x512 weights
    PrepW p5;
    p5.w[0] = w_q;   p5.wh[0] = wq_h; p5.wl[0] = wq_l;
    p5.w[1] = w_k;   p5.wh[1] = wk_h; p5.wl[1] = wk_l;
    p5.w[2] = w_v;   p5.wh[2] = wv_h; p5.wl[2] = wv_l;
    p5.w[3] = w_o;   p5.wh[3] = wo_h; p5.wl[3] = wo_l;
    p5.w[4] = w_pos; p5.wh[4] = wp_h; p5.wl[4] = wp_l;
    prep_wb<<<dim3(16, 16, 5), blk, 0, stream>>>(p5);

    // 3) effective weights: Wq/k/v_eff = Wqkv_slice @ W*, Wo_eff = Wao @ Wo
    WeffA wa;
    wa.ah[0] = wqkvh;        wa.al[0] = wqkvl;        wa.lda[0] = 1536;
    wa.ah[1] = wqkvh + 512;  wa.al[1] = wqkvl + 512;  wa.lda[1] = 1536;
    wa.ah[2] = wqkvh + 1024; wa.al[2] = wqkvl + 1024; wa.lda[2] = 1536;
    wa.ah[3] = waoh;         wa.al[3] = waol;         wa.lda[3] = 512;
    wa.wh[0] = wq_h; wa.wl[0] = wq_l;
    wa.wh[1] = wk_h; wa.wl[1] = wk_l;
    wa.wh[2] = wv_h; wa.wl[2] = wv_l;
    wa.wh[3] = wo_h; wa.wl[3] = wo_l;
    wa.c[0] = weffC;             wa.c[1] = weffC + 262144;
    wa.c[2] = weffC + 2*262144;  wa.c[3] = weffC + 3*262144;
    gemm_weff<<<dim3(4, 8, 4), blk, 0, stream>>>(wa);

    // 4) transpose+split effective weights (q|k|v concat + wo_eff)
    PrepW p4;
    p4.w[0] = weffC;            p4.wh[0] = wcat_h;            p4.wl[0] = wcat_l;
    p4.w[1] = weffC + 262144;   p4.wh[1] = wcat_h + 262144;   p4.wl[1] = wcat_l + 262144;
    p4.w[2] = weffC + 2*262144; p4.wh[2] = wcat_h + 2*262144; p4.wl[2] = wcat_l + 2*262144;
    p4.w[3] = weffC + 3*262144; p4.wh[3] = woe_h;             p4.wl[3] = woe_l;
    p4.w[4] = nullptr; p4.wh[4] = nullptr; p4.wl[4] = nullptr;
    prep_wb<<<dim3(16, 16, 4), blk, 0, stream>>>(p4);

    // 5) bias_eff + pb slack zero
    misc_k<<<3, blk, 0, stream>>>(b_ao, w_o, b_o, beff, pb_base);

    // 6) fused q/k/v projection + pos projection (2-term split; bf16 outputs)
    gemm_qkv<<<dim3(12, 64), blk, 0, stream>>>(xh, wcat_h, wcat_l,
        b_q, bu, bv, b_k, b_v, qu, qv, kb, vt);
    gemm_pos<<<dim3(4, 16), blk, 0, stream>>>(posh, wp_h, wp_l, pb0);

    // 7) attention
    attn_v8<<<1024, blk, 0, stream>>>(qu, qv, kb, vt, pb0, atth, attl);

    // 8) output GEMM
    gemm_out<<<dim3(4, 128), blk, 0, stream>>>(atth, attl, woe_h, woe_l, beff, out);
}